// Round 12
// baseline (1836.578 us; speedup 1.0000x reference)
//
#include <hip/hip_runtime.h>
#include <stdint.h>

typedef unsigned short u16;
typedef __attribute__((ext_vector_type(8))) __bf16 bf16x8;
typedef __attribute__((ext_vector_type(4))) float f32x4;
typedef __attribute__((ext_vector_type(16))) float f32x16;

#define SEQ     4096
#define DMODEL  2048
#define DINNER  4096
#define NHEADS  64
#define HEADP   64
#define NSTATE  128
#define NCHUNK  16
#define CHUNKL  256
#define NPROJ   8512
#define NPROJP  8576
#define CONVDIM 4352
#define RESM    0.22f
#define MAXROWS 9216
#define MAXTILE 72

static __device__ __forceinline__ u16 f2bf(float f){
  union { float f; uint32_t u; } v; v.f = f;
  uint32_t r = v.u + 0x7fffu + ((v.u >> 16) & 1u);
  return (u16)(r >> 16);
}
static __device__ __forceinline__ float bf2f(u16 h){
  union { uint32_t u; float f; } v; v.u = ((uint32_t)h) << 16;
  return v.f;
}
static __device__ __forceinline__ float siluf(float x){ return x / (1.f + __expf(-x)); }

// async global->LDS, 16B per lane
static __device__ __forceinline__ void gll16(const void* g, void* l) {
  __builtin_amdgcn_global_load_lds(
      (const __attribute__((address_space(1))) void*)g,
      (__attribute__((address_space(3))) void*)l, 16, 0, 0);
}

// LDS bank-conflict swizzle (free; conflicts measured 0 since r8)
static __device__ __forceinline__ int swz_src_c8(int tid) {
  return ((((tid & 3) - ((tid >> 3) & 3) + 4) & 3) * 8);
}
static __device__ __forceinline__ int swz_rd_sl8(int fr, int g) {
  return (((g + ((fr >> 1) & 3)) & 3) * 8);
}

// XCD-chunked bijective swizzle + G-column L2 grouping (nwg % 8 == 0 for all users).
static __device__ __forceinline__ void decode_tile(
    int id, int NB, int MB, int G, int& bx, int& by)
{
  const int nwg = NB * MB;
  int sid = id;
  if (!(nwg & 7)) {
    const int cpx = nwg >> 3;
    sid = (id & 7) * cpx + (id >> 3);
  }
  const int gsz = MB * G;
  const int fullG = NB / G;
  const int fullCnt = fullG * gsz;
  if (sid < fullCnt) {
    const int grp = sid / gsz;
    const int r = sid - grp * gsz;
    const int q = r / G;
    by = q;
    bx = grp * G + (r - q * G);
  } else {
    const int rem = NB - fullG * G;
    const int r = sid - fullCnt;
    const int q = r / rem;
    by = q;
    bx = fullG * G + (r - q * rem);
  }
}

// ---------------- rmsnorm: f32 in -> bf16 hi+lo split ----------------
__global__ __launch_bounds__(256) void rmsnorm_split(
    const float* __restrict__ in, const float* __restrict__ w,
    u16* __restrict__ hi, u16* __restrict__ lo, int width)
{
  const int row = blockIdx.x;
  const float* x = in + (size_t)row * width;
  float ss = 0.f;
  for (int i = threadIdx.x * 4; i < width; i += 1024) {
    float4 v = *(const float4*)&x[i];
    ss += v.x*v.x + v.y*v.y + v.z*v.z + v.w*v.w;
  }
  #pragma unroll
  for (int off = 32; off > 0; off >>= 1) ss += __shfl_down(ss, off);
  __shared__ float red[4];
  if ((threadIdx.x & 63) == 0) red[threadIdx.x >> 6] = ss;
  __syncthreads();
  const float total = red[0] + red[1] + red[2] + red[3];
  const float scale = rsqrtf(total / (float)width + 1e-5f);
  u16* oh = hi + (size_t)row * width;
  u16* ol = lo + (size_t)row * width;
  for (int i = threadIdx.x * 4; i < width; i += 1024) {
    float4 v = *(const float4*)&x[i];
    float4 g = *(const float4*)&w[i];
    #pragma unroll
    for (int q = 0; q < 4; q++) {
      const float val = ((const float*)&v)[q] * scale * ((const float*)&g)[q];
      const u16 H = f2bf(val);
      oh[i+q] = H;
      ol[i+q] = f2bf(val - bf2f(H));
    }
  }
}

// ---------- weight convert+transpose: W (K x N) f32 -> Bt (N x K) bf16 ----------
__global__ __launch_bounds__(256) void wconv_t(
    const float* __restrict__ W, u16* __restrict__ Bt, int K, int N)
{
  const size_t eo = (size_t)blockIdx.z * K * N;
  W += eo; Bt += eo;
  __shared__ float t[32][33];
  const int n0 = blockIdx.x * 32, k0 = blockIdx.y * 32;
  const int tx = threadIdx.x & 31, ty = threadIdx.x >> 5;
  #pragma unroll
  for (int r = 0; r < 32; r += 8)
    t[ty + r][tx] = W[(size_t)(k0 + ty + r) * N + n0 + tx];
  __syncthreads();
  #pragma unroll
  for (int r = 0; r < 32; r += 8)
    Bt[(size_t)(n0 + ty + r) * K + k0 + tx] = f2bf(t[tx][ty + r]);
}

// ---------- weight convert+transpose with gate/up column interleave ----------
__global__ __launch_bounds__(256) void wconv_t_glu(
    const float* __restrict__ W, u16* __restrict__ Bt, int K, int N, int H)
{
  const size_t eo = (size_t)blockIdx.z * K * N;
  W += eo; Bt += eo;
  __shared__ float t[32][33];
  const int n0 = blockIdx.x * 32, k0 = blockIdx.y * 32;
  const int tx = threadIdx.x & 31, ty = threadIdx.x >> 5;
  #pragma unroll
  for (int r = 0; r < 32; r += 8)
    t[ty + r][tx] = W[(size_t)(k0 + ty + r) * N + n0 + tx];
  __syncthreads();
  #pragma unroll
  for (int r = 0; r < 32; r += 8) {
    const int n = n0 + ty + r;
    const int orow = (n < H) ? (2 * n) : (2 * (n - H) + 1);
    Bt[(size_t)orow * K + k0 + tx] = f2bf(t[tx][ty + r]);
  }
}

// ---------- weight convert+transpose with hi/lo split ----------
__global__ __launch_bounds__(256) void wconv_t_split(
    const float* __restrict__ W, u16* __restrict__ Bth, u16* __restrict__ Btl, int K, int N)
{
  __shared__ float t[32][33];
  const int n0 = blockIdx.x * 32, k0 = blockIdx.y * 32;
  const int tx = threadIdx.x & 31, ty = threadIdx.x >> 5;
  #pragma unroll
  for (int r = 0; r < 32; r += 8)
    t[ty + r][tx] = W[(size_t)(k0 + ty + r) * N + n0 + tx];
  __syncthreads();
  #pragma unroll
  for (int r = 0; r < 32; r += 8) {
    const float val = t[tx][ty + r];
    const u16 H = f2bf(val);
    const size_t idx = (size_t)(n0 + ty + r) * K + k0 + tx;
    Bth[idx] = H;
    Btl[idx] = f2bf(val - bf2f(H));
  }
}

// ---------------- GEMM: C[M,N] = A[M,K] * Bt[N,K]^T, EPI 3: C f32 = acc ----------------
template<int EPI>
__global__ __launch_bounds__(256, 2) void gemm_bt(
    const u16* __restrict__ A, const u16* __restrict__ Bt,
    float* __restrict__ Cf,
    int Nreal, int K, int ldc, int NB, int MB, int G)
{
  __shared__ u16 As[128 * 32];
  __shared__ u16 Bs[128 * 32];
  int bx, by; decode_tile(blockIdx.x, NB, MB, G, bx, by);
  const int tid = threadIdx.x, lane = tid & 63;
  const int wid = tid >> 6, wr = wid >> 1, wc = wid & 1;
  const int m0 = by * 128, n0 = bx * 128;
  const int fr = lane & 15, g = lane >> 4;
  const int sl8 = swz_rd_sl8(fr, g);
  const f32x4 zero = {0.f, 0.f, 0.f, 0.f};
  f32x4 acc[4][4];
  #pragma unroll
  for (int i = 0; i < 4; i++)
    #pragma unroll
    for (int j = 0; j < 4; j++) acc[i][j] = zero;
  const int c8 = swz_src_c8(tid);
  const u16* pA = A  + (size_t)(m0 + (tid >> 2)) * K + c8;
  const u16* pB = Bt + (size_t)(n0 + (tid >> 2)) * K + c8;
  const size_t rstep = (size_t)64 * K;
  const int l0 = tid * 8;
  for (int k0 = 0; k0 < K; k0 += 32) {
    if (k0) __syncthreads();
    gll16(pA + k0,         &As[l0]);
    gll16(pA + k0 + rstep, &As[2048 + l0]);
    gll16(pB + k0,         &Bs[l0]);
    gll16(pB + k0 + rstep, &Bs[2048 + l0]);
    __syncthreads();
    bf16x8 af[4], bfr[4];
    #pragma unroll
    for (int mi = 0; mi < 4; mi++)
      af[mi] = *(const bf16x8*)&As[(wr * 64 + mi * 16 + fr) * 32 + sl8];
    #pragma unroll
    for (int ni = 0; ni < 4; ni++)
      bfr[ni] = *(const bf16x8*)&Bs[(wc * 64 + ni * 16 + fr) * 32 + sl8];
    #pragma unroll
    for (int mi = 0; mi < 4; mi++)
      #pragma unroll
      for (int ni = 0; ni < 4; ni++)
        acc[mi][ni] = __builtin_amdgcn_mfma_f32_16x16x32_bf16(af[mi], bfr[ni], acc[mi][ni], 0, 0, 0);
  }
  #pragma unroll
  for (int mi = 0; mi < 4; mi++) {
    #pragma unroll
    for (int ni = 0; ni < 4; ni++) {
      const int n = n0 + wc * 64 + ni * 16 + fr;
      if (n >= Nreal) continue;
      #pragma unroll
      for (int i = 0; i < 4; i++) {
        const int m = m0 + wr * 64 + mi * 16 + g * 4 + i;
        Cf[(size_t)m * ldc + n] = acc[mi][ni][i];
      }
    }
  }
}

// ---------------- GEMM with fused GLU epilogue (interleaved B) ----------------
__global__ __launch_bounds__(256, 2) void gemm_bt_glu(
    const u16* __restrict__ A, const u16* __restrict__ Bt,
    u16* __restrict__ aout,
    int K, int Nhalf, int NB, int MB, int G)
{
  __shared__ u16 As[128 * 32];
  __shared__ u16 Bs[128 * 32];
  int bx, by; decode_tile(blockIdx.x, NB, MB, G, bx, by);
  const int tid = threadIdx.x, lane = tid & 63;
  const int wid = tid >> 6, wr = wid >> 1, wc = wid & 1;
  const int m0 = by * 128, n0 = bx * 128;
  const int fr = lane & 15, g = lane >> 4;
  const int sl8 = swz_rd_sl8(fr, g);
  const f32x4 zero = {0.f, 0.f, 0.f, 0.f};
  f32x4 acc[4][4];
  #pragma unroll
  for (int i = 0; i < 4; i++)
    #pragma unroll
    for (int j = 0; j < 4; j++) acc[i][j] = zero;
  const int c8 = swz_src_c8(tid);
  const u16* pA = A  + (size_t)(m0 + (tid >> 2)) * K + c8;
  const u16* pB = Bt + (size_t)(n0 + (tid >> 2)) * K + c8;
  const size_t rstep = (size_t)64 * K;
  const int l0 = tid * 8;
  for (int k0 = 0; k0 < K; k0 += 32) {
    if (k0) __syncthreads();
    gll16(pA + k0,         &As[l0]);
    gll16(pA + k0 + rstep, &As[2048 + l0]);
    gll16(pB + k0,         &Bs[l0]);
    gll16(pB + k0 + rstep, &Bs[2048 + l0]);
    __syncthreads();
    bf16x8 af[4], bfr[4];
    #pragma unroll
    for (int mi = 0; mi < 4; mi++)
      af[mi] = *(const bf16x8*)&As[(wr * 64 + mi * 16 + fr) * 32 + sl8];
    #pragma unroll
    for (int ni = 0; ni < 4; ni++)
      bfr[ni] = *(const bf16x8*)&Bs[(wc * 64 + ni * 16 + fr) * 32 + sl8];
    #pragma unroll
    for (int mi = 0; mi < 4; mi++)
      #pragma unroll
      for (int ni = 0; ni < 4; ni++)
        acc[mi][ni] = __builtin_amdgcn_mfma_f32_16x16x32_bf16(af[mi], bfr[ni], acc[mi][ni], 0, 0, 0);
  }
  #pragma unroll
  for (int mi = 0; mi < 4; mi++) {
    #pragma unroll
    for (int ni = 0; ni < 4; ni++) {
      const int n = n0 + wc * 64 + ni * 16 + fr;
      #pragma unroll
      for (int i = 0; i < 4; i++) {
        const float v = acc[mi][ni][i];
        const float vp = __shfl_xor(v, 1);
        if (!(fr & 1)) {
          const int m = m0 + wr * 64 + mi * 16 + g * 4 + i;
          aout[(size_t)m * Nhalf + (n >> 1)] = f2bf(siluf(v) * vp);
        }
      }
    }
  }
}

// ---------------- double-bf16 GEMM, 32x32x16 MFMA: 3-term (hh + hl + lh) ----------------
// EPI 1: C f32 = res + alpha*acc ; EPI 3: C f32 = acc
template<int EPI>
__global__ __launch_bounds__(256, 2) void gemm_dd(
    const u16* __restrict__ Ah, const u16* __restrict__ Al,
    const u16* __restrict__ Bh, const u16* __restrict__ Bl,
    float* __restrict__ Cf, const float* __restrict__ res,
    int Nreal, int K, int ldc, float alpha, int NB, int MB, int G)
{
  __shared__ u16 Ash[128 * 32];
  __shared__ u16 Asl[128 * 32];
  __shared__ u16 Bsh[128 * 32];
  __shared__ u16 Bsl[128 * 32];
  int bx, by; decode_tile(blockIdx.x, NB, MB, G, bx, by);
  const int tid = threadIdx.x, lane = tid & 63;
  const int wid = tid >> 6, wr = wid >> 1, wc = wid & 1;
  const int m0 = by * 128, n0 = bx * 128;
  const int r32 = lane & 31, kg = lane >> 5;   // 32x32 fragment coords
  const int sbase = (r32 >> 1) & 3;            // swizzle base for this row
  f32x16 acc[2][2];
  #pragma unroll
  for (int i = 0; i < 2; i++)
    #pragma unroll
    for (int j = 0; j < 2; j++)
      #pragma unroll
      for (int q = 0; q < 16; q++) acc[i][j][q] = 0.f;
  const int c8 = swz_src_c8(tid);
  const size_t offA = (size_t)(m0 + (tid >> 2)) * K + c8;
  const size_t offB = (size_t)(n0 + (tid >> 2)) * K + c8;
  const size_t rstep = (size_t)64 * K;
  const int l0 = tid * 8;
  for (int k0 = 0; k0 < K; k0 += 32) {
    if (k0) __syncthreads();
    gll16(Ah + offA + k0,         &Ash[l0]);
    gll16(Ah + offA + k0 + rstep, &Ash[2048 + l0]);
    gll16(Al + offA + k0,         &Asl[l0]);
    gll16(Al + offA + k0 + rstep, &Asl[2048 + l0]);
    gll16(Bh + offB + k0,         &Bsh[l0]);
    gll16(Bh + offB + k0 + rstep, &Bsh[2048 + l0]);
    gll16(Bl + offB + k0,         &Bsl[l0]);
    gll16(Bl + offB + k0 + rstep, &Bsl[2048 + l0]);
    __syncthreads();
    bf16x8 ah[2][2], al[2][2], bh[2][2], bl[2][2];   // [tile][k-slice]
    #pragma unroll
    for (int at = 0; at < 2; at++)
      #pragma unroll
      for (int ks = 0; ks < 2; ks++) {
        const int row = wr * 64 + at * 32 + r32;
        const int a = row * 32 + (((ks * 2 + kg) + sbase) & 3) * 8;
        ah[at][ks] = *(const bf16x8*)&Ash[a];
        al[at][ks] = *(const bf16x8*)&Asl[a];
      }
    #pragma unroll
    for (int bt = 0; bt < 2; bt++)
      #pragma unroll
      for (int ks = 0; ks < 2; ks++) {
        const int row = wc * 64 + bt * 32 + r32;
        const int b = row * 32 + (((ks * 2 + kg) + sbase) & 3) * 8;
        bh[bt][ks] = *(const bf16x8*)&Bsh[b];
        bl[bt][ks] = *(const bf16x8*)&Bsl[b];
      }
    #pragma unroll
    for (int at = 0; at < 2; at++)
      #pragma unroll
      for (int bt = 0; bt < 2; bt++)
        #pragma unroll
        for (int ks = 0; ks < 2; ks++) {
          acc[at][bt] = __builtin_amdgcn_mfma_f32_32x32x16_bf16(al[at][ks], bh[bt][ks], acc[at][bt], 0, 0, 0);
          acc[at][bt] = __builtin_amdgcn_mfma_f32_32x32x16_bf16(ah[at][ks], bl[bt][ks], acc[at][bt], 0, 0, 0);
          acc[at][bt] = __builtin_amdgcn_mfma_f32_32x32x16_bf16(ah[at][ks], bh[bt][ks], acc[at][bt], 0, 0, 0);
        }
  }
  // epilogue: C/D layout col = lane&31, row = (r&3) + 8*(r>>2) + 4*(lane>>5)
  #pragma unroll
  for (int at = 0; at < 2; at++)
    #pragma unroll
    for (int bt = 0; bt < 2; bt++) {
      const int n = n0 + wc * 64 + bt * 32 + r32;
      if (n >= Nreal) continue;
      #pragma unroll
      for (int r = 0; r < 16; r++) {
        const int m = m0 + wr * 64 + at * 32 + (r & 3) + 8 * (r >> 2) + 4 * kg;
        const float v = acc[at][bt][r];
        const size_t idx = (size_t)m * ldc + n;
        if constexpr (EPI == 1) {
          Cf[idx] = res[idx] + alpha * v;
        } else {
          Cf[idx] = v;
        }
      }
    }
}

// ---------------- packed MoE gate_up GEMM + fused GLU (interleaved wGU) ----------------
__global__ __launch_bounds__(256, 2) void gemm_moe_gu(
    const u16* __restrict__ ht, const u16* __restrict__ wGU,
    u16* __restrict__ abufp, const int* __restrict__ tokmap,
    const int* __restrict__ meta)
{
  const int by = blockIdx.y;
  if (by >= meta[24]) return;
  const int e = meta[32 + by];
  const int row0 = meta[104 + by];
  __shared__ u16 As[128 * 32];
  __shared__ u16 Bs[128 * 32];
  const int tid = threadIdx.x, lane = tid & 63;
  const int wid = tid >> 6, wr = wid >> 1, wc = wid & 1;
  const int n0 = blockIdx.x * 128;
  const int fr = lane & 15, g = lane >> 4;
  const int sl8 = swz_rd_sl8(fr, g);
  const f32x4 zero = {0.f, 0.f, 0.f, 0.f};
  f32x4 acc[4][4];
  #pragma unroll
  for (int i = 0; i < 4; i++)
    #pragma unroll
    for (int j = 0; j < 4; j++) acc[i][j] = zero;
  const int r4 = tid >> 2, c8 = swz_src_c8(tid);
  const int tok0 = tokmap[row0 + r4];
  const int tok1 = tokmap[row0 + 64 + r4];
  const u16* pA0 = ht + (size_t)tok0 * DMODEL + c8;
  const u16* pA1 = ht + (size_t)tok1 * DMODEL + c8;
  const u16* pB  = wGU + (size_t)e * 2048 * DMODEL + (size_t)(n0 + r4) * DMODEL + c8;
  const size_t rstep = (size_t)64 * DMODEL;
  const int l0 = tid * 8;
  for (int k0 = 0; k0 < DMODEL; k0 += 32) {
    if (k0) __syncthreads();
    gll16(pA0 + k0,        &As[l0]);
    gll16(pA1 + k0,        &As[2048 + l0]);
    gll16(pB + k0,         &Bs[l0]);
    gll16(pB + k0 + rstep, &Bs[2048 + l0]);
    __syncthreads();
    bf16x8 af[4], bfr[4];
    #pragma unroll
    for (int mi = 0; mi < 4; mi++)
      af[mi] = *(const bf16x8*)&As[(wr * 64 + mi * 16 + fr) * 32 + sl8];
    #pragma unroll
    for (int ni = 0; ni < 4; ni++)
      bfr[ni] = *(const bf16x8*)&Bs[(wc * 64 + ni * 16 + fr) * 32 + sl8];
    #pragma unroll
    for (int mi = 0; mi < 4; mi++)
      #pragma unroll
      for (int ni = 0; ni < 4; ni++)
        acc[mi][ni] = __builtin_amdgcn_mfma_f32_16x16x32_bf16(af[mi], bfr[ni], acc[mi][ni], 0, 0, 0);
  }
  #pragma unroll
  for (int mi = 0; mi < 4; mi++)
    #pragma unroll
    for (int ni = 0; ni < 4; ni++) {
      const int n = n0 + wc * 64 + ni * 16 + fr;
      #pragma unroll
      for (int i = 0; i < 4; i++) {
        const float v = acc[mi][ni][i];
        const float vp = __shfl_xor(v, 1);
        if (!(fr & 1)) {
          const int m = row0 + wr * 64 + mi * 16 + g * 4 + i;
          abufp[(size_t)m * 1024 + (n >> 1)] = f2bf(siluf(v) * vp);
        }
      }
    }
}

// ---------------- packed MoE down GEMM ----------------
__global__ __launch_bounds__(256, 2) void gemm_moe_down(
    const u16* __restrict__ abuf, const u16* __restrict__ wDN,
    u16* __restrict__ dout, const float* __restrict__ gatew,
    const int* __restrict__ meta)
{
  const int by = blockIdx.y;
  if (by >= meta[24]) return;
  const int e = meta[32 + by];
  const int row0 = meta[104 + by];
  __shared__ u16 As[128 * 32];
  __shared__ u16 Bs[128 * 32];
  const int tid = threadIdx.x, lane = tid & 63;
  const int wid = tid >> 6, wr = wid >> 1, wc = wid & 1;
  const int n0 = blockIdx.x * 128;
  const int fr = lane & 15, g = lane >> 4;
  const int sl8 = swz_rd_sl8(fr, g);
  const f32x4 zero = {0.f, 0.f, 0.f, 0.f};
  f32x4 acc[4][4];
  #pragma unroll
  for (int i = 0; i < 4; i++)
    #pragma unroll
    for (int j = 0; j < 4; j++) acc[i][j] = zero;
  const int r4 = tid >> 2, c8 = swz_src_c8(tid);
  const u16* pA = abuf + (size_t)(row0 + r4) * 1024 + c8;
  const u16* pB = wDN + (size_t)e * 1024 * 2048 + (size_t)(n0 + r4) * 1024 + c8;
  const size_t rstepA = (size_t)64 * 1024;
  const int l0 = tid * 8;
  for (int k0 = 0; k0 < 1024; k0 += 32) {
    if (k0) __syncthreads();
    gll16(pA + k0,          &As[l0]);
    gll16(pA + k0 + rstepA, &As[2048 + l0]);
    gll16(pB + k0,          &Bs[l0]);
    gll16(pB + k0 + rstepA, &Bs[2048 + l0]);
    __syncthreads();
    bf16x8 af[4], bfr[4];
    #pragma unroll
    for (int mi = 0; mi < 4; mi++)
      af[mi] = *(const bf16x8*)&As[(wr * 64 + mi * 16 + fr) * 32 + sl8];
    #pragma unroll
    for (int ni = 0; ni < 4; ni++)
      bfr[ni] = *(const bf16x8*)&Bs[(wc * 64 + ni * 16 + fr) * 32 + sl8];
    #pragma unroll
    for (int mi = 0; mi < 4; mi++)
      #pragma unroll
      for (int ni = 0; ni < 4; ni++)
        acc[mi][ni] = __builtin_amdgcn_mfma_f32_16x16x32_bf16(af[mi], bfr[ni], acc[mi][ni], 0, 0, 0);
  }
  #pragma unroll
  for (int mi = 0; mi < 4; mi++)
    #pragma unroll
    for (int ni = 0; ni < 4; ni++) {
      const int n = n0 + wc * 64 + ni * 16 + fr;
      #pragma unroll
      for (int i = 0; i < 4; i++) {
        const int m = row0 + wr * 64 + mi * 16 + g * 4 + i;
        dout[(size_t)m * 2048 + n] = f2bf(acc[mi][ni][i] * gatew[m]);
      }
    }
}

// ---------------- fused causal conv+silu+split AND dt softplus ----------------
__global__ __launch_bounds__(256) void conv_silu_dt(
    const float* __restrict__ proj, const float* __restrict__ cw, const float* __restrict__ cb,
    const float* __restrict__ dt_bias,
    float* __restrict__ x, float* __restrict__ Bc, float* __restrict__ Cc,
    float* __restrict__ dt)
{
  const int c = blockIdx.x * 256 + threadIdx.x;
  const int s = blockIdx.y;
  if (c < CONVDIM) {
    const float4 w = *(const float4*)&cw[c * 4];
    float acc = cb[c];
    const float* pc = proj + (size_t)DINNER + c;
    if (s >= 3) acc += pc[(size_t)(s-3) * NPROJP] * w.x;
    if (s >= 2) acc += pc[(size_t)(s-2) * NPROJP] * w.y;
    if (s >= 1) acc += pc[(size_t)(s-1) * NPROJP] * w.z;
    acc += pc[(size_t)s * NPROJP] * w.w;
    const float v = siluf(acc);
    if (c < DINNER)                 x[(size_t)s * DINNER + c] = v;
    else if (c < DINNER + NSTATE)   Bc[(size_t)s * NSTATE + (c - DINNER)] = v;
    else                            Cc[(size_t)s * NSTATE + (c - DINNER - NSTATE)] = v;
  } else if (c < CONVDIM + 64) {
    const int h = c - CONVDIM;
    const float v = proj[(size_t)s * NPROJP + (DINNER + CONVDIM) + h] + dt_bias[h];
    dt[(size_t)s * 64 + h] = fmaxf(v, 0.f) + log1pf(__expf(-fabsf(v)));
  }
}

// ---------------- sequential-order cumsum of dA ----------------
__global__ __launch_bounds__(64) void ssd_cum_seq(
    const float* __restrict__ dt, const float* __restrict__ A_log,
    float* __restrict__ cum, float* __restrict__ cdec)
{
  const int c = blockIdx.x, h = threadIdx.x;
  const float A = -__expf(A_log[h]);
  float run = 0.f;
  float* co = cum + ((size_t)(c * 64 + h)) * 256;
  const float* dp = dt + (size_t)c * 256 * 64 + h;
  #pragma unroll 4
  for (int l = 0; l < 256; l++) {
    run += dp[(size_t)l * 64] * A;
    co[l] = run;
  }
  cdec[c * 64 + h] = __expf(run);
}

// ---------------- CBt ----------------
__global__ __launch_bounds__(256) void ssd_cb(
    const float* __restrict__ Cc, const float* __restrict__ Bc, float* __restrict__ CBt)
{
  const int c = blockIdx.y;
  const int lt = blockIdx.x >> 2, st = blockIdx.x & 3;
  if (st > lt) return;
  __shared__ float Cn[128][64];
  __shared__ float Bn[128][64];
  const int tid = threadIdx.x;
  #pragma unroll
  for (int rep = 0; rep < 8; rep++) {
    const int lin = rep * 1024 + tid * 4;
    const int r = lin >> 7, cc = lin & 127;
    float4 cv = *(const float4*)&Cc[((size_t)(c*256 + lt*64 + r)) * 128 + cc];
    float4 bv = *(const float4*)&Bc[((size_t)(c*256 + st*64 + r)) * 128 + cc];
    Cn[cc+0][r] = cv.x; Cn[cc+1][r] = cv.y; Cn[cc+2][r] = cv.z; Cn[cc+3][r] = cv.w;
    Bn[cc+0][r] = bv.x; Bn[cc+1][r] = bv.y; Bn[cc+2][r] = bv.z; Bn[cc+3][r] = bv.w;
  }
  __syncthreads();
  const int lb = (tid >> 4) * 4, sb = (tid & 15) * 4;
  float acc[4][4] = {};
  for (int n = 0; n < 128; n++) {
    float cv[4], bv[4];
    #pragma unroll
    for (int i = 0; i < 4; i++) { cv[i] = Cn[n][lb+i]; bv[i] = Bn[n][sb+i]; }
    #pragma unroll
    for (int i = 0; i < 4; i++)
      #pragma unroll
      for (int j = 0; j < 4; j++) acc[i][j] += cv[i] * bv[j];
  }
  #pragma unroll
  for (int is = 0; is < 4; is++) {
    const int sg = st*64 + sb + is;
    float4 o; o.x = acc[0][is]; o.y = acc[1][is]; o.z = acc[2][is]; o.w = acc[3][is];
    *(float4*)&CBt[((size_t)(c*256 + sg)) * 256 + lt*64 + lb] = o;
  }
}

// ---------------- chunk states via MFMA (hi/lo 3-term) ----------------
__global__ __launch_bounds__(256, 2) void ssd_states_mfma(
    const float* __restrict__ x, const float* __restrict__ Bc, const float* __restrict__ dt,
    const float* __restrict__ cum, float* __restrict__ states)
{
  const int c = blockIdx.x, h = blockIdx.y;
  const int tid = threadIdx.x, lane = tid & 63, w = tid >> 6;
  const int fr = lane & 15, g = lane >> 4;
  __shared__ float cd[256];
  __shared__ u16 Xth[64 * 32],  Xtl[64 * 32];
  __shared__ u16 Bth[128 * 32], Btl[128 * 32];
  {
    const float* cumh = cum + ((size_t)(c*64 + h)) * 256;
    cd[tid] = __expf(cumh[255] - cumh[tid]) * dt[(size_t)(c*256 + tid) * 64 + h];
  }
  const f32x4 zero = {0.f, 0.f, 0.f, 0.f};
  f32x4 acc[4][2];
  #pragma unroll
  for (int i = 0; i < 4; i++) { acc[i][0] = zero; acc[i][1] = zero; }
  for (int lt = 0; lt < 8; lt++) {
    __syncthreads();
    {
      const int ll = tid >> 3, p0 = (tid & 7) * 8;
      const int lg = c*256 + lt*32 + ll;
      const float cdv = cd[lt*32 + ll];
      const float* xr = x + (size_t)lg * DINNER + h*64 + p0;
      const float4 v0 = *(const float4*)&xr[0];
      const float4 v1 = *(const float4*)&xr[4];
      #pragma unroll
      for (int q = 0; q < 8; q++) {
        const float v = ((q < 4) ? ((const float*)&v0)[q] : ((const float*)&v1)[q-4]) * cdv;
        const u16 H = f2bf(v);
        Xth[(p0 + q) * 32 + ll] = H;
        Xtl[(p0 + q) * 32 + ll] = f2bf(v - bf2f(H));
      }
    }
    {
      const int ll = tid >> 3, n0 = (tid & 7) * 16;
      const float* br = Bc + (size_t)(c*256 + lt*32 + ll) * 128 + n0;
      #pragma unroll
      for (int q4 = 0; q4 < 4; q4++) {
        const float4 bv = *(const float4*)&br[q4*4];
        #pragma unroll
        for (int q = 0; q < 4; q++) {
          const float v = ((const float*)&bv)[q];
          const u16 H = f2bf(v);
          Bth[(n0 + q4*4 + q) * 32 + ll] = H;
          Btl[(n0 + q4*4 + q) * 32 + ll] = f2bf(v - bf2f(H));
        }
      }
    }
    __syncthreads();
    bf16x8 ah[4], al[4], bh[2], bl[2];
    #pragma unroll
    for (int mi = 0; mi < 4; mi++) {
      const int a = (mi*16 + fr) * 32 + g*8;
      ah[mi] = *(const bf16x8*)&Xth[a];
      al[mi] = *(const bf16x8*)&Xtl[a];
    }
    #pragma unroll
    for (int ni = 0; ni < 2; ni++) {
      const int b = (w*32 + ni*16 + fr) * 32 + g*8;
      bh[ni] = *(const bf16x8*)&Bth[b];
      bl[ni] = *(const bf16x8*)&Btl[b];
    }
    #pragma unroll
    for (int mi = 0; mi < 4; mi++)
      #pragma unroll
      for (int ni = 0; ni < 2; ni++) {
        acc[mi][ni] = __builtin_amdgcn_mfma_f32_16x16x32_bf16(al[mi], bh[ni], acc[mi][ni], 0, 0, 0);
        acc[mi][ni] = __builtin_amdgcn_mfma_f32_16x16x32_bf16(ah[mi], bl[ni], acc[mi][ni], 0, 0, 0);
        acc[mi][ni] = __builtin_amdgcn_mfma_f32_16x16x32_bf16(ah[mi], bh[ni], acc[mi][ni], 0, 0, 0);
      }
  }
  #pragma unroll
  for (int mi = 0; mi < 4; mi++)
    #pragma unroll
    for (int ni = 0; ni < 2; ni++)
      #pragma unroll
      for (int i = 0; i < 4; i++) {
        const int p = mi*16 + g*4 + i;
        const int n = w*32 + ni*16 + fr;
        states[(((size_t)(c*64 + h)) * 64 + p) * 128 + n] = acc[mi][ni][i];
      }
}

// ---------------- sequential scan over the 16 chunks ----------------
__global__ void ssd_scan(
    const float* __restrict__ states, const float* __restrict__ cdec, float* __restrict__ prev)
{
  const int hp = blockIdx.x;
  const int n = threadIdx.x;
  const int h = hp >> 6;
  float carry = 0.f;
  for (int c = 0; c < NCHUNK; c++) {
    const size_t idx = ((size_t)c * 4096 + hp) * 128 + n;
    prev[idx] = carry;
    carry = carry * cdec[c*64 + h] + states[idx];
  }
}

// ---------------- FUSED intra + inter Y via MFMA (3-term) + D*x + silu(z) gating ----------------
// phase1: Y += P·Xd (causal, 8 ts tiles); phase2: Y += (C·odec)·prev^T (4 nt tiles, odec folded
// into C staging since MFMA can't scale mid-accumulate); epilogue: +D*x, *silu(z), one Y write.
__global__ __launch_bounds__(256, 2) void ssd_intra_final_mfma(
    const float* __restrict__ x, const float* __restrict__ dt, const float* __restrict__ cum,
    const float* __restrict__ CBt, const float* __restrict__ Cc, const float* __restrict__ prev,
    const float* __restrict__ proj, const float* __restrict__ Dp, float* __restrict__ Yw)
{
  const int c = blockIdx.x, h = blockIdx.y;
  const int tid = threadIdx.x, lane = tid & 63, w = tid >> 6;
  const int fr = lane & 15, g = lane >> 4;
  __shared__ float cumL[256];
  __shared__ float odecL[256];
  __shared__ u16 Ph[256 * 32], Pl[256 * 32];   // phase2 reuse: Ch/Cl
  __shared__ u16 Xh[64 * 32],  Xl[64 * 32];    // phase2 reuse: Pvh/Pvl
  cumL[tid] = cum[((size_t)(c*64 + h)) * 256 + tid];
  odecL[tid] = __expf(cumL[tid]);
  const f32x4 zero = {0.f, 0.f, 0.f, 0.f};
  f32x4 acc[4][4];
  #pragma unroll
  for (int i = 0; i < 4; i++)
    #pragma unroll
    for (int j = 0; j < 4; j++) acc[i][j] = zero;
  const size_t cb0 = (size_t)c * 65536;
  // ---- phase 1: intra-chunk ----
  for (int ts = 0; ts < 8; ts++) {
    __syncthreads();
    {   // stage Xd tile (32 s x 64 p) transposed -> Xh/Xl [p][s]
      const int sl = tid >> 3, p0 = (tid & 7) * 8;
      const int sg = c*256 + ts*32 + sl;
      const float dtv = dt[(size_t)sg * 64 + h];
      const float* xr = x + (size_t)sg * DINNER + h*64 + p0;
      const float4 v0 = *(const float4*)&xr[0];
      const float4 v1 = *(const float4*)&xr[4];
      #pragma unroll
      for (int q = 0; q < 8; q++) {
        const float v = ((q < 4) ? ((const float*)&v0)[q] : ((const float*)&v1)[q-4]) * dtv;
        const u16 H = f2bf(v);
        Xh[(p0 + q) * 32 + sl] = H;
        Xl[(p0 + q) * 32 + sl] = f2bf(v - bf2f(H));
      }
    }
    {   // build P tile (256 l x 32 s) hi/lo
      const int l = tid;
      const float myc = cumL[l];
      #pragma unroll 4
      for (int j = 0; j < 32; j++) {
        const int s = ts*32 + j;
        const float cb = CBt[cb0 + (size_t)s * 256 + l];
        float p = 0.f;
        if (s <= l) p = cb * __expf(myc - cumL[s]);
        const u16 H = f2bf(p);
        Ph[l * 32 + j] = H;
        Pl[l * 32 + j] = f2bf(p - bf2f(H));
      }
    }
    __syncthreads();
    if (ts * 32 < (w + 1) * 64) {
      bf16x8 ah[4], al[4], bh[4], bl[4];
      #pragma unroll
      for (int mi = 0; mi < 4; mi++) {
        const int a = (w*64 + mi*16 + fr) * 32 + g*8;
        ah[mi] = *(const bf16x8*)&Ph[a];
        al[mi] = *(const bf16x8*)&Pl[a];
      }
      #pragma unroll
      for (int ni = 0; ni < 4; ni++) {
        const int b = (ni*16 + fr) * 32 + g*8;
        bh[ni] = *(const bf16x8*)&Xh[b];
        bl[ni] = *(const bf16x8*)&Xl[b];
      }
      #pragma unroll
      for (int mi = 0; mi < 4; mi++)
        #pragma unroll
        for (int ni = 0; ni < 4; ni++) {
          acc[mi][ni] = __builtin_amdgcn_mfma_f32_16x16x32_bf16(al[mi], bh[ni], acc[mi][ni], 0, 0, 0);
          acc[mi][ni] = __builtin_amdgcn_mfma_f32_16x16x32_bf16(ah[mi], bl[ni], acc[mi][ni], 0, 0, 0);
          acc[mi][ni] = __builtin_amdgcn_mfma_f32_16x16x32_bf16(ah[mi], bh[ni], acc[mi][ni], 0, 0, 0);
        }
    }
  }
  // ---- phase 2: inter-chunk, C pre-scaled by odec ----
  for (int nt = 0; nt < 4; nt++) {
    __syncthreads();
    {   // stage C*odec tile (256 l x 32 n) hi/lo into Ph/Pl
      #pragma unroll
      for (int rep = 0; rep < 32; rep++) {
        const int l = rep*8 + (tid >> 5);
        const int j = tid & 31;
        const float v = Cc[(size_t)(c*256 + l) * 128 + nt*32 + j] * odecL[l];
        const u16 H = f2bf(v);
        Ph[l*32 + j] = H;
        Pl[l*32 + j] = f2bf(v - bf2f(H));
      }
    }
    {   // stage prev tile (64 p x 32 n) hi/lo into Xh/Xl
      const int p = tid >> 2, q0 = (tid & 3) * 8;
      const float* pr = prev + ((size_t)c * 4096 + h*64 + p) * 128 + nt*32 + q0;
      const float4 v0 = *(const float4*)&pr[0];
      const float4 v1 = *(const float4*)&pr[4];
      #pragma unroll
      for (int q = 0; q < 8; q++) {
        const float v = (q < 4) ? ((const float*)&v0)[q] : ((const float*)&v1)[q-4];
        const u16 H = f2bf(v);
        Xh[p*32 + q0 + q] = H;
        Xl[p*32 + q0 + q] = f2bf(v - bf2f(H));
      }
    }
    __syncthreads();
    bf16x8 ah[4], al[4], bh[4], bl[4];
    #pragma unroll
    for (int mi = 0; mi < 4; mi++) {
      const int a = (w*64 + mi*16 + fr) * 32 + g*8;
      ah[mi] = *(const bf16x8*)&Ph[a];
      al[mi] = *(const bf16x8*)&Pl[a];
    }
    #pragma unroll
    for (int ni = 0; ni < 4; ni++) {
      const int b = (ni*16 + fr) * 32 + g*8;
      bh[ni] = *(const bf16x8*)&Xh[b];
      bl[ni] = *(const bf16x8*)&Xl[b];
    }
    #pragma unroll
    for (int mi = 0; mi < 4; mi++)
      #pragma unroll
      for (int ni = 0; ni < 4; ni++) {
        acc[mi][ni] = __builtin_amdgcn_mfma_f32_16x16x32_bf16(al[mi], bh[ni], acc[mi][ni], 0, 0, 0);
        acc[mi][ni] = __builtin_amdgcn_mfma_f32_16x16x32_bf16(ah[mi], bl[ni], acc[mi][ni], 0, 0, 0);
        acc[mi][ni] = __builtin_amdgcn_mfma_f32_16x16x32_bf16(ah[mi], bh[ni], acc[mi][ni], 0, 0, 0);
      }
  }
  // ---- epilogue: +D*x, gate by silu(z), single Y write ----
  const float Dv = Dp[h];
  #pragma unroll
  for (int mi = 0; mi < 4; mi++) {
    #pragma unroll
    for (int i = 0; i < 4; i++) {
      const int l = w*64 + mi*16 + g*4 + i;
      const size_t rowo = (size_t)(c*256 + l);
      #pragma unroll
      for (int ni = 0; ni < 4; ni++) {
        const int p = ni*16 + fr;
        const size_t iy = rowo * DINNER + h*64 + p;
        const float yv = acc[mi][ni][i] + Dv * x[iy];
        const float z = proj[rowo * NPROJP + h*64 + p];
        Yw[iy] = yv * siluf(z);
      }
    }
  }
}

// ---------------- fused: rmsnorm(hidden2)->ht bf16 AND router top-2 ----------------
__global__ __launch_bounds__(256) void router_norm(
    const float* __restrict__ h2, const float* __restrict__ ln2w,
    const float* __restrict__ rw, u16* __restrict__ ht,
    int* __restrict__ eidx, float* __restrict__ ew)
{
  const int t = blockIdx.x;
  const float* xr = h2 + (size_t)t * DMODEL;
  float ss = 0.f;
  for (int i = threadIdx.x * 4; i < DMODEL; i += 1024) {
    float4 v = *(const float4*)&xr[i];
    ss += v.x*v.x + v.y*v.y + v.z*v.z + v.w*v.w;
  }
  #pragma unroll
  for (int off = 32; off > 0; off >>= 1) ss += __shfl_down(ss, off);
  __shared__ float red[4];
  if ((threadIdx.x & 63) == 0) red[threadIdx.x >> 6] = ss;
  __syncthreads();
  const float scale = rsqrtf((red[0]+red[1]+red[2]+red[3]) / (float)DMODEL + 1e-5f);
  float acc[8];
  #pragma unroll
  for (int j = 0; j < 8; j++) acc[j] = 0.f;
  u16* o = ht + (size_t)t * DMODEL;
  for (int i = threadIdx.x; i < DMODEL; i += 256) {
    const float v = xr[i] * scale * ln2w[i];
    o[i] = f2bf(v);
    const float* r = rw + (size_t)i * 8;
    #pragma unroll
    for (int j = 0; j < 8; j++) acc[j] += v * r[j];
  }
  #pragma unroll
  for (int j = 0; j < 8; j++)
    #pragma unroll
    for (int off = 32; off > 0; off >>= 1) acc[j] += __shfl_down(acc[j], off);
  __shared__ float rbuf[4][8];
  if ((threadIdx.x & 63) == 0)
    #pragma unroll
    for (int j = 0; j < 8; j++) rbuf[threadIdx.x >> 6][j] = acc[j];
  __syncthreads();
  if (threadIdx.x == 0) {
    float lg[8];
    #pragma unroll
    for (int j = 0; j < 8; j++) lg[j] = rbuf[0][j]+rbuf[1][j]+rbuf[2][j]+rbuf[3][j];
    int i1 = 0;
    #pragma unroll
    for (int j = 1; j < 8; j++) if (lg[j] > lg[i1]) i1 = j;
    int i2 = -1;
    #pragma unroll
    for (int j = 0; j < 8; j++) if (j != i1 && (i2 < 0 || lg[j] > lg[i2])) i2 = j;
    const float e2 = __expf(lg[i2] - lg[i1]);
    const float inv = 1.f / (1.f + e2);
    eidx[t*2]   = i1;  ew[t*2]   = inv;
    eidx[t*2+1] = i2;  ew[t*2+1] = e2 * inv;
  }
}

// ---------------- single-block MoE routing: zero + count + offsets + place ----------------
__global__ __launch_bounds__(1024) void moe_route(
    const int* __restrict__ eidx, const float* __restrict__ ew,
    int* __restrict__ tokmap, float* __restrict__ gatew,
    int* __restrict__ posmap, int* __restrict__ meta)
{
  const int tid = threadIdx.x;
  __shared__ int cnt[8], base[8];
  if (tid < 8) cnt[tid] = 0;
  for (int i = tid; i < MAXROWS; i += 1024) tokmap[i] = 0;
  __syncthreads();
  for (int i = tid; i < SEQ * 2; i += 1024)
    atomicAdd(&cnt[eidx[i]], 1);
  __syncthreads();
  if (tid == 0) {
    int off = 0, T = 0;
    for (int e = 0; e < 8; e++) {
      base[e] = off;
      meta[16 + e] = off;
      const int nt = (cnt[e] + 127) >> 7;
      for (int j = 0; j < nt; j++) {
        meta[32 + T] = e;
        meta[104 + T] = off + j * 128;
        T++;
      }
      off += nt * 128;
      cnt[e] = 0;          // reuse as placement cursor
    }
    meta[24] = T;
  }
  __syncthreads();
  for (int i = tid; i < SEQ * 2; i += 1024) {
    const int e = eidx[i];
    const int pos = atomicAdd(&cnt[e], 1);
    const int r = base[e] + pos;
    tokmap[r] = i >> 1;
    gatew[r] = ew[i];
    posmap[i] = r;
  }
}

// ---------------- out0 = h2 + RESM*(shared + dout[pos0] + dout[pos1]) ----------------
__global__ __launch_bounds__(256) void final_moe(
    const float* __restrict__ h2, const float* __restrict__ shout,
    const u16* __restrict__ dout, const int* __restrict__ posmap,
    float* __restrict__ o)
{
  const int t = blockIdx.x;
  const int p0 = posmap[t*2], p1 = posmap[t*2+1];
  const u16* d0 = dout + (size_t)p0 * 2048 + threadIdx.x * 8;
  const u16* d1 = dout + (size_t)p1 * 2048 + threadIdx.x * 8;
  const size_t base = (size_t)t * 2048 + threadIdx.x * 8;
  #pragma unroll
  for (int q = 0; q < 8; q++) {
    const float ff = shout[base + q] + bf2f(d0[q]) + bf2f(d1[q]);
    o[base + q] = h2[base + q] + RESM * ff;
  }
}

// ---------------- workspace layout (bytes) ----------------
#define OFF_WAH   ((size_t)0)
#define OFF_WAL   ((size_t)35127296)
#define OFF_PROJ  ((size_t)70254592)
#define OFF_X     ((size_t)210763776)
#define OFF_Y     ((size_t)277872640)
#define OFF_HP    ((size_t)344981504)
#define OFF_BC    ((size_t)378535936)
#define OFF_CC    ((size_t)380633088)
#define OFF_DT    ((size_t)382730240)
#define OFF_CUM   ((size_t)383778816)
#define OFF_CDEC  ((size_t)384827392)
#define OFF_CB    ((size_t)384831488)

extern "C" void kernel_launch(void* const* d_in, const int* in_sizes, int n_in,
                              void* d_out, int out_size, void* d_ws, size_t ws_size,
                              hipStream_t stream)
{
  const float* hs       = (const float*)d_in[1];
  const float* ln1_w    = (const float*)d_in[2];
  const float* w_inproj = (const float*)d_in[3];
  const float* conv_w   = (const float*)d_in[4];
  const float* conv_b   = (const float*)d_in[5];
  const float* A_log    = (const float*)d_in[6];
  const float* dt_bias  = (const float*)d_in[7];
  const float* D_param  = (const float*)d_in[8];
  const float* mnorm_w  = (const float*)d_in[9];
  const float* w_outp   = (const float*)d_in[10];
  const float* ln2_w    = (const float*)d_in[11];
  const float* router_w = (const float*)d_in[12];
  const float* w_gu     = (const float*)d_in[13];
  const float* w_down   = (const float*)d_in[14];
  const float* w_shin   = (const float*)d_in[15];
  const float* w_shout  = (const float*)d_in[16];

  char* ws = (char*)d_ws;
  u16*   wAh    = (u16*)(ws + OFF_WAH);
  u16*   wAl    = (u16*)(ws + OFF_WAL);
  float* projf  = (float*)(ws + OFF_PROJ);
  float* xbuf   = (float*)(ws + OFF_X);
  float* ybuf   = (float*)(ws + OFF_Y);
  float* Bcb    = (float*)(ws + OFF_BC);
  float* Ccb    = (float*)(ws + OFF_CC);
  float* dtb    = (float*)(ws + OFF_DT);
  float* cumb   = (float*)(ws + OFF_CUM);
  float* cdecb  = (float*)(ws + OFF_CDEC);
  float* cbt    = (float*)(ws + OFF_CB);

  // lifetime-overlapped aliases
  u16*   hhi    = (u16*)(ws + OFF_HP);
  u16*   hlo    = (u16*)(ws + OFF_HP + 16777216);
  float* prevb  = (float*)(ws + OFF_HP);
  u16*   wDN    = (u16*)(ws + OFF_HP);                   // 32MiB after prev dead
  float* stbuf  = (float*)(ws + OFF_WAH);
  u16*   ynhi   = (u16*)(ws + OFF_WAH);
  u16*   ynlo   = (u16*)(ws + OFF_WAL);
  u16*   wBh    = (u16*)(ws + OFF_PROJ);
  u16*   wBl    = (u16*)(ws + OFF_PROJ + 16777216);
  u16*   wE     = (u16*)(ws + OFF_WAH);                  // shared-in Wt interleaved (33.5M)
  u16*   wD     = (u16*)(ws + OFF_WAH + 33554432);       // shared-out Wt (16.8M)
  u16*   wGU    = (u16*)(ws + OFF_WAH);                  // expert gate_up Wt interleaved (64M)
  u16*   abufp  = (u16*)(ws + OFF_PROJ + 83886080);      // packed a bf16 (18.9M)
  u16*   ht     = (u16*)(ws + OFF_X);
  u16*   ash    = (u16*)(ws + OFF_X + 16777216);         // shared a bf16 (33.5M)
  u16*   dout   = (u16*)(ws + OFF_X + 16777216);         // packed dout bf16, after ash dead
  float* shout  = (float*)(ws + OFF_Y);

  int*   eidx   = (int*)(ws + OFF_BC);
  float* ew     = (float*)(ws + OFF_BC + 65536);
  int*   posmap = (int*)(ws + OFF_BC + 131072);
  int*   tokmap = (int*)(ws + OFF_BC + 196608);
  float* gatew  = (float*)(ws + OFF_BC + 262144);
  int*   meta   = (int*)(ws + OFF_BC + 327680);

  float* out0    = (float*)d_out;
  float* hidden2 = out0 + (size_t)SEQ * DMODEL;

  // ---- Mamba block ----
  rmsnorm_split<<<SEQ, 256, 0, stream>>>(hs, ln1_w, hhi, hlo, DMODEL);
  wconv_t_split<<<dim3(NPROJ/32, DMODEL/32), 256, 0, stream>>>(w_inproj, wAh, wAl, DMODEL, NPROJ);
  gemm_dd<3><<<67*32, 256, 0, stream>>>(hhi, hlo, wAh, wAl, projf, nullptr,
                                        NPROJ, DMODEL, NPROJP, 0.f, 67, 32, 4);
  conv_silu_dt<<<dim3(18, SEQ), 256, 0, stream>>>(projf, conv_w, conv_b, dt_bias,
                                                  xbuf, Bcb, Ccb, dtb);
  ssd_cum_seq<<<NCHUNK, 64, 0, stream>>>(dtb, A_log, cumb, cdecb);
  ssd_cb<<<dim3(16, NCHUNK), 256, 0, stream>>>(Ccb, Bcb, cbt);
  ssd_states_mfma<<<dim3(NCHUNK, NHEADS), 256, 0, stream>>>(xbuf, Bcb, dtb, cumb, stbuf);
  ssd_scan<<<NHEADS*HEADP, 128, 0, stream>>>(stbuf, cdecb, prevb);
  ssd_intra_final_mfma<<<dim3(NCHUNK, NHEADS), 256, 0, stream>>>(
      xbuf, dtb, cumb, cbt, Ccb, prevb, projf, D_param, ybuf);
  rmsnorm_split<<<SEQ, 256, 0, stream>>>(ybuf, mnorm_w, ynhi, ynlo, DINNER);
  wconv_t_split<<<dim3(DMODEL/32, DINNER/32), 256, 0, stream>>>(w_outp, wBh, wBl, DINNER, DMODEL);
  gemm_dd<1><<<16*32, 256, 0, stream>>>(ynhi, ynlo, wBh, wBl, hidden2, hs,
                                        DMODEL, DINNER, DMODEL, RESM, 16, 32, 4);

  // ---- Router + ht norm (fused) + single-kernel token packing ----
  router_norm<<<SEQ, 256, 0, stream>>>(hidden2, ln2_w, router_w, ht, eidx, ew);
  moe_route<<<1, 1024, 0, stream>>>(eidx, ew, tokmap, gatew, posmap, meta);

  // ---- Shared expert (dense, GLU fused into gate_up GEMM) ----
  wconv_t_glu<<<dim3(8192/32, DMODEL/32), 256, 0, stream>>>(w_shin, wE, DMODEL, 8192, 4096);
  gemm_bt_glu<<<64*32, 256, 0, stream>>>(ht, wE, ash, DMODEL, 4096, 64, 32, 4);
  wconv_t<<<dim3(DMODEL/32, 4096/32), 256, 0, stream>>>(w_shout, wD, 4096, DMODEL);
  gemm_bt<3><<<16*32, 256, 0, stream>>>(ash, wD, shout, DMODEL, 4096, DMODEL, 16, 32, 4);

  // ---- Sparse top-2 experts (packed, GLU fused) ----
  wconv_t_glu<<<dim3(2048/32, DMODEL/32, 8), 256, 0, stream>>>(w_gu, wGU, DMODEL, 2048, 1024);
  wconv_t<<<dim3(DMODEL/32, 1024/32, 8), 256, 0, stream>>>(w_down, wDN, 1024, DMODEL);
  gemm_moe_gu<<<dim3(16, MAXTILE), 256, 0, stream>>>(ht, wGU, abufp, tokmap, meta);
  gemm_moe_down<<<dim3(16, MAXTILE), 256, 0, stream>>>(abufp, wDN, dout, gatew, meta);

  final_moe<<<SEQ, 256, 0, stream>>>(hidden2, shout, dout, posmap, out0);
}

// Round 13
// 1762.222 us; speedup vs baseline: 1.0422x; 1.0422x over previous
//
#include <hip/hip_runtime.h>
#include <stdint.h>

typedef unsigned short u16;
typedef __attribute__((ext_vector_type(8))) __bf16 bf16x8;
typedef __attribute__((ext_vector_type(4))) float f32x4;

#define SEQ     4096
#define DMODEL  2048
#define DINNER  4096
#define NHEADS  64
#define HEADP   64
#define NSTATE  128
#define NCHUNK  16
#define CHUNKL  256
#define NPROJ   8512
#define NPROJP  8576
#define CONVDIM 4352
#define RESM    0.22f
#define MAXROWS 9216
#define MAXTILE 72

static __device__ __forceinline__ u16 f2bf(float f){
  union { float f; uint32_t u; } v; v.f = f;
  uint32_t r = v.u + 0x7fffu + ((v.u >> 16) & 1u);
  return (u16)(r >> 16);
}
static __device__ __forceinline__ float bf2f(u16 h){
  union { uint32_t u; float f; } v; v.u = ((uint32_t)h) << 16;
  return v.f;
}
static __device__ __forceinline__ float siluf(float x){ return x / (1.f + __expf(-x)); }

// async global->LDS, 16B per lane
static __device__ __forceinline__ void gll16(const void* g, void* l) {
  __builtin_amdgcn_global_load_lds(
      (const __attribute__((address_space(1))) void*)g,
      (__attribute__((address_space(3))) void*)l, 16, 0, 0);
}

// LDS bank-conflict swizzle (free; conflicts measured 0 since r8)
static __device__ __forceinline__ int swz_src_c8(int tid) {
  return ((((tid & 3) - ((tid >> 3) & 3) + 4) & 3) * 8);
}
static __device__ __forceinline__ int swz_rd_sl8(int fr, int g) {
  return (((g + ((fr >> 1) & 3)) & 3) * 8);
}

// XCD-chunked bijective swizzle + G-column L2 grouping (nwg % 8 == 0 for all users).
static __device__ __forceinline__ void decode_tile(
    int id, int NB, int MB, int G, int& bx, int& by)
{
  const int nwg = NB * MB;
  int sid = id;
  if (!(nwg & 7)) {
    const int cpx = nwg >> 3;
    sid = (id & 7) * cpx + (id >> 3);
  }
  const int gsz = MB * G;
  const int fullG = NB / G;
  const int fullCnt = fullG * gsz;
  if (sid < fullCnt) {
    const int grp = sid / gsz;
    const int r = sid - grp * gsz;
    const int q = r / G;
    by = q;
    bx = grp * G + (r - q * G);
  } else {
    const int rem = NB - fullG * G;
    const int r = sid - fullCnt;
    const int q = r / rem;
    by = q;
    bx = fullG * G + (r - q * rem);
  }
}

// ---------------- rmsnorm: f32 in -> bf16 hi+lo split ----------------
__global__ __launch_bounds__(256) void rmsnorm_split(
    const float* __restrict__ in, const float* __restrict__ w,
    u16* __restrict__ hi, u16* __restrict__ lo, int width)
{
  const int row = blockIdx.x;
  const float* x = in + (size_t)row * width;
  float ss = 0.f;
  for (int i = threadIdx.x * 4; i < width; i += 1024) {
    float4 v = *(const float4*)&x[i];
    ss += v.x*v.x + v.y*v.y + v.z*v.z + v.w*v.w;
  }
  #pragma unroll
  for (int off = 32; off > 0; off >>= 1) ss += __shfl_down(ss, off);
  __shared__ float red[4];
  if ((threadIdx.x & 63) == 0) red[threadIdx.x >> 6] = ss;
  __syncthreads();
  const float total = red[0] + red[1] + red[2] + red[3];
  const float scale = rsqrtf(total / (float)width + 1e-5f);
  u16* oh = hi + (size_t)row * width;
  u16* ol = lo + (size_t)row * width;
  for (int i = threadIdx.x * 4; i < width; i += 1024) {
    float4 v = *(const float4*)&x[i];
    float4 g = *(const float4*)&w[i];
    #pragma unroll
    for (int q = 0; q < 4; q++) {
      const float val = ((const float*)&v)[q] * scale * ((const float*)&g)[q];
      const u16 H = f2bf(val);
      oh[i+q] = H;
      ol[i+q] = f2bf(val - bf2f(H));
    }
  }
}

// ---------- weight convert+transpose: W (K x N) f32 -> Bt (N x K) bf16 ----------
__global__ __launch_bounds__(256) void wconv_t(
    const float* __restrict__ W, u16* __restrict__ Bt, int K, int N)
{
  const size_t eo = (size_t)blockIdx.z * K * N;
  W += eo; Bt += eo;
  __shared__ float t[32][33];
  const int n0 = blockIdx.x * 32, k0 = blockIdx.y * 32;
  const int tx = threadIdx.x & 31, ty = threadIdx.x >> 5;
  #pragma unroll
  for (int r = 0; r < 32; r += 8)
    t[ty + r][tx] = W[(size_t)(k0 + ty + r) * N + n0 + tx];
  __syncthreads();
  #pragma unroll
  for (int r = 0; r < 32; r += 8)
    Bt[(size_t)(n0 + ty + r) * K + k0 + tx] = f2bf(t[tx][ty + r]);
}

// ---------- weight convert+transpose with gate/up column interleave ----------
__global__ __launch_bounds__(256) void wconv_t_glu(
    const float* __restrict__ W, u16* __restrict__ Bt, int K, int N, int H)
{
  const size_t eo = (size_t)blockIdx.z * K * N;
  W += eo; Bt += eo;
  __shared__ float t[32][33];
  const int n0 = blockIdx.x * 32, k0 = blockIdx.y * 32;
  const int tx = threadIdx.x & 31, ty = threadIdx.x >> 5;
  #pragma unroll
  for (int r = 0; r < 32; r += 8)
    t[ty + r][tx] = W[(size_t)(k0 + ty + r) * N + n0 + tx];
  __syncthreads();
  #pragma unroll
  for (int r = 0; r < 32; r += 8) {
    const int n = n0 + ty + r;
    const int orow = (n < H) ? (2 * n) : (2 * (n - H) + 1);
    Bt[(size_t)orow * K + k0 + tx] = f2bf(t[tx][ty + r]);
  }
}

// ---------- weight convert+transpose with hi/lo split ----------
__global__ __launch_bounds__(256) void wconv_t_split(
    const float* __restrict__ W, u16* __restrict__ Bth, u16* __restrict__ Btl, int K, int N)
{
  __shared__ float t[32][33];
  const int n0 = blockIdx.x * 32, k0 = blockIdx.y * 32;
  const int tx = threadIdx.x & 31, ty = threadIdx.x >> 5;
  #pragma unroll
  for (int r = 0; r < 32; r += 8)
    t[ty + r][tx] = W[(size_t)(k0 + ty + r) * N + n0 + tx];
  __syncthreads();
  #pragma unroll
  for (int r = 0; r < 32; r += 8) {
    const float val = t[tx][ty + r];
    const u16 H = f2bf(val);
    const size_t idx = (size_t)(n0 + ty + r) * K + k0 + tx;
    Bth[idx] = H;
    Btl[idx] = f2bf(val - bf2f(H));
  }
}

// ---------------- GEMM: C[M,N] = A[M,K] * Bt[N,K]^T, EPI 3: C f32 = acc ----------------
template<int EPI>
__global__ __launch_bounds__(256, 2) void gemm_bt(
    const u16* __restrict__ A, const u16* __restrict__ Bt,
    float* __restrict__ Cf,
    int Nreal, int K, int ldc, int NB, int MB, int G)
{
  __shared__ u16 As[128 * 32];
  __shared__ u16 Bs[128 * 32];
  int bx, by; decode_tile(blockIdx.x, NB, MB, G, bx, by);
  const int tid = threadIdx.x, lane = tid & 63;
  const int wid = tid >> 6, wr = wid >> 1, wc = wid & 1;
  const int m0 = by * 128, n0 = bx * 128;
  const int fr = lane & 15, g = lane >> 4;
  const int sl8 = swz_rd_sl8(fr, g);
  const f32x4 zero = {0.f, 0.f, 0.f, 0.f};
  f32x4 acc[4][4];
  #pragma unroll
  for (int i = 0; i < 4; i++)
    #pragma unroll
    for (int j = 0; j < 4; j++) acc[i][j] = zero;
  const int c8 = swz_src_c8(tid);
  const u16* pA = A  + (size_t)(m0 + (tid >> 2)) * K + c8;
  const u16* pB = Bt + (size_t)(n0 + (tid >> 2)) * K + c8;
  const size_t rstep = (size_t)64 * K;
  const int l0 = tid * 8;
  for (int k0 = 0; k0 < K; k0 += 32) {
    if (k0) __syncthreads();
    gll16(pA + k0,         &As[l0]);
    gll16(pA + k0 + rstep, &As[2048 + l0]);
    gll16(pB + k0,         &Bs[l0]);
    gll16(pB + k0 + rstep, &Bs[2048 + l0]);
    __syncthreads();
    bf16x8 af[4], bfr[4];
    #pragma unroll
    for (int mi = 0; mi < 4; mi++)
      af[mi] = *(const bf16x8*)&As[(wr * 64 + mi * 16 + fr) * 32 + sl8];
    #pragma unroll
    for (int ni = 0; ni < 4; ni++)
      bfr[ni] = *(const bf16x8*)&Bs[(wc * 64 + ni * 16 + fr) * 32 + sl8];
    #pragma unroll
    for (int mi = 0; mi < 4; mi++)
      #pragma unroll
      for (int ni = 0; ni < 4; ni++)
        acc[mi][ni] = __builtin_amdgcn_mfma_f32_16x16x32_bf16(af[mi], bfr[ni], acc[mi][ni], 0, 0, 0);
  }
  #pragma unroll
  for (int mi = 0; mi < 4; mi++) {
    #pragma unroll
    for (int ni = 0; ni < 4; ni++) {
      const int n = n0 + wc * 64 + ni * 16 + fr;
      if (n >= Nreal) continue;
      #pragma unroll
      for (int i = 0; i < 4; i++) {
        const int m = m0 + wr * 64 + mi * 16 + g * 4 + i;
        Cf[(size_t)m * ldc + n] = acc[mi][ni][i];
      }
    }
  }
}

// ---------------- GEMM with fused GLU epilogue (interleaved B) ----------------
__global__ __launch_bounds__(256, 2) void gemm_bt_glu(
    const u16* __restrict__ A, const u16* __restrict__ Bt,
    u16* __restrict__ aout,
    int K, int Nhalf, int NB, int MB, int G)
{
  __shared__ u16 As[128 * 32];
  __shared__ u16 Bs[128 * 32];
  int bx, by; decode_tile(blockIdx.x, NB, MB, G, bx, by);
  const int tid = threadIdx.x, lane = tid & 63;
  const int wid = tid >> 6, wr = wid >> 1, wc = wid & 1;
  const int m0 = by * 128, n0 = bx * 128;
  const int fr = lane & 15, g = lane >> 4;
  const int sl8 = swz_rd_sl8(fr, g);
  const f32x4 zero = {0.f, 0.f, 0.f, 0.f};
  f32x4 acc[4][4];
  #pragma unroll
  for (int i = 0; i < 4; i++)
    #pragma unroll
    for (int j = 0; j < 4; j++) acc[i][j] = zero;
  const int c8 = swz_src_c8(tid);
  const u16* pA = A  + (size_t)(m0 + (tid >> 2)) * K + c8;
  const u16* pB = Bt + (size_t)(n0 + (tid >> 2)) * K + c8;
  const size_t rstep = (size_t)64 * K;
  const int l0 = tid * 8;
  for (int k0 = 0; k0 < K; k0 += 32) {
    if (k0) __syncthreads();
    gll16(pA + k0,         &As[l0]);
    gll16(pA + k0 + rstep, &As[2048 + l0]);
    gll16(pB + k0,         &Bs[l0]);
    gll16(pB + k0 + rstep, &Bs[2048 + l0]);
    __syncthreads();
    bf16x8 af[4], bfr[4];
    #pragma unroll
    for (int mi = 0; mi < 4; mi++)
      af[mi] = *(const bf16x8*)&As[(wr * 64 + mi * 16 + fr) * 32 + sl8];
    #pragma unroll
    for (int ni = 0; ni < 4; ni++)
      bfr[ni] = *(const bf16x8*)&Bs[(wc * 64 + ni * 16 + fr) * 32 + sl8];
    #pragma unroll
    for (int mi = 0; mi < 4; mi++)
      #pragma unroll
      for (int ni = 0; ni < 4; ni++)
        acc[mi][ni] = __builtin_amdgcn_mfma_f32_16x16x32_bf16(af[mi], bfr[ni], acc[mi][ni], 0, 0, 0);
  }
  #pragma unroll
  for (int mi = 0; mi < 4; mi++) {
    #pragma unroll
    for (int ni = 0; ni < 4; ni++) {
      const int n = n0 + wc * 64 + ni * 16 + fr;
      #pragma unroll
      for (int i = 0; i < 4; i++) {
        const float v = acc[mi][ni][i];
        const float vp = __shfl_xor(v, 1);
        if (!(fr & 1)) {
          const int m = m0 + wr * 64 + mi * 16 + g * 4 + i;
          aout[(size_t)m * Nhalf + (n >> 1)] = f2bf(siluf(v) * vp);
        }
      }
    }
  }
}

// ---------------- double-bf16 GEMM: 3-term (hh + hl + lh), 16x16x32 ----------------
// EPI 1: C f32 = res + alpha*acc ; EPI 3: C f32 = acc
template<int EPI>
__global__ __launch_bounds__(256, 2) void gemm_dd(
    const u16* __restrict__ Ah, const u16* __restrict__ Al,
    const u16* __restrict__ Bh, const u16* __restrict__ Bl,
    float* __restrict__ Cf, const float* __restrict__ res,
    int Nreal, int K, int ldc, float alpha, int NB, int MB, int G)
{
  __shared__ u16 Ash[128 * 32];
  __shared__ u16 Asl[128 * 32];
  __shared__ u16 Bsh[128 * 32];
  __shared__ u16 Bsl[128 * 32];
  int bx, by; decode_tile(blockIdx.x, NB, MB, G, bx, by);
  const int tid = threadIdx.x, lane = tid & 63;
  const int wid = tid >> 6, wr = wid >> 1, wc = wid & 1;
  const int m0 = by * 128, n0 = bx * 128;
  const int fr = lane & 15, g = lane >> 4;
  const int sl8 = swz_rd_sl8(fr, g);
  const f32x4 zero = {0.f, 0.f, 0.f, 0.f};
  f32x4 acc[4][4];
  #pragma unroll
  for (int i = 0; i < 4; i++)
    #pragma unroll
    for (int j = 0; j < 4; j++) acc[i][j] = zero;
  const int c8 = swz_src_c8(tid);
  const size_t offA = (size_t)(m0 + (tid >> 2)) * K + c8;
  const size_t offB = (size_t)(n0 + (tid >> 2)) * K + c8;
  const size_t rstep = (size_t)64 * K;
  const int l0 = tid * 8;
  for (int k0 = 0; k0 < K; k0 += 32) {
    if (k0) __syncthreads();
    gll16(Ah + offA + k0,         &Ash[l0]);
    gll16(Ah + offA + k0 + rstep, &Ash[2048 + l0]);
    gll16(Al + offA + k0,         &Asl[l0]);
    gll16(Al + offA + k0 + rstep, &Asl[2048 + l0]);
    gll16(Bh + offB + k0,         &Bsh[l0]);
    gll16(Bh + offB + k0 + rstep, &Bsh[2048 + l0]);
    gll16(Bl + offB + k0,         &Bsl[l0]);
    gll16(Bl + offB + k0 + rstep, &Bsl[2048 + l0]);
    __syncthreads();
    bf16x8 ah[4], al[4], bh[4], bl[4];
    #pragma unroll
    for (int mi = 0; mi < 4; mi++) {
      const int a = (wr * 64 + mi * 16 + fr) * 32 + sl8;
      ah[mi] = *(const bf16x8*)&Ash[a];
      al[mi] = *(const bf16x8*)&Asl[a];
    }
    #pragma unroll
    for (int ni = 0; ni < 4; ni++) {
      const int b = (wc * 64 + ni * 16 + fr) * 32 + sl8;
      bh[ni] = *(const bf16x8*)&Bsh[b];
      bl[ni] = *(const bf16x8*)&Bsl[b];
    }
    #pragma unroll
    for (int mi = 0; mi < 4; mi++)
      #pragma unroll
      for (int ni = 0; ni < 4; ni++) {
        acc[mi][ni] = __builtin_amdgcn_mfma_f32_16x16x32_bf16(al[mi], bh[ni], acc[mi][ni], 0, 0, 0);
        acc[mi][ni] = __builtin_amdgcn_mfma_f32_16x16x32_bf16(ah[mi], bl[ni], acc[mi][ni], 0, 0, 0);
        acc[mi][ni] = __builtin_amdgcn_mfma_f32_16x16x32_bf16(ah[mi], bh[ni], acc[mi][ni], 0, 0, 0);
      }
  }
  #pragma unroll
  for (int mi = 0; mi < 4; mi++) {
    #pragma unroll
    for (int ni = 0; ni < 4; ni++) {
      const int n = n0 + wc * 64 + ni * 16 + fr;
      if (n >= Nreal) continue;
      #pragma unroll
      for (int i = 0; i < 4; i++) {
        const int m = m0 + wr * 64 + mi * 16 + g * 4 + i;
        const float v = acc[mi][ni][i];
        const size_t idx = (size_t)m * ldc + n;
        if constexpr (EPI == 1) {
          Cf[idx] = res[idx] + alpha * v;
        } else {
          Cf[idx] = v;
        }
      }
    }
  }
}

// ---------------- packed MoE gate_up GEMM + fused GLU (interleaved wGU) ----------------
__global__ __launch_bounds__(256, 2) void gemm_moe_gu(
    const u16* __restrict__ ht, const u16* __restrict__ wGU,
    u16* __restrict__ abufp, const int* __restrict__ tokmap,
    const int* __restrict__ meta)
{
  const int by = blockIdx.y;
  if (by >= meta[24]) return;
  const int e = meta[32 + by];
  const int row0 = meta[104 + by];
  __shared__ u16 As[128 * 32];
  __shared__ u16 Bs[128 * 32];
  const int tid = threadIdx.x, lane = tid & 63;
  const int wid = tid >> 6, wr = wid >> 1, wc = wid & 1;
  const int n0 = blockIdx.x * 128;
  const int fr = lane & 15, g = lane >> 4;
  const int sl8 = swz_rd_sl8(fr, g);
  const f32x4 zero = {0.f, 0.f, 0.f, 0.f};
  f32x4 acc[4][4];
  #pragma unroll
  for (int i = 0; i < 4; i++)
    #pragma unroll
    for (int j = 0; j < 4; j++) acc[i][j] = zero;
  const int r4 = tid >> 2, c8 = swz_src_c8(tid);
  const int tok0 = tokmap[row0 + r4];
  const int tok1 = tokmap[row0 + 64 + r4];
  const u16* pA0 = ht + (size_t)tok0 * DMODEL + c8;
  const u16* pA1 = ht + (size_t)tok1 * DMODEL + c8;
  const u16* pB  = wGU + (size_t)e * 2048 * DMODEL + (size_t)(n0 + r4) * DMODEL + c8;
  const size_t rstep = (size_t)64 * DMODEL;
  const int l0 = tid * 8;
  for (int k0 = 0; k0 < DMODEL; k0 += 32) {
    if (k0) __syncthreads();
    gll16(pA0 + k0,        &As[l0]);
    gll16(pA1 + k0,        &As[2048 + l0]);
    gll16(pB + k0,         &Bs[l0]);
    gll16(pB + k0 + rstep, &Bs[2048 + l0]);
    __syncthreads();
    bf16x8 af[4], bfr[4];
    #pragma unroll
    for (int mi = 0; mi < 4; mi++)
      af[mi] = *(const bf16x8*)&As[(wr * 64 + mi * 16 + fr) * 32 + sl8];
    #pragma unroll
    for (int ni = 0; ni < 4; ni++)
      bfr[ni] = *(const bf16x8*)&Bs[(wc * 64 + ni * 16 + fr) * 32 + sl8];
    #pragma unroll
    for (int mi = 0; mi < 4; mi++)
      #pragma unroll
      for (int ni = 0; ni < 4; ni++)
        acc[mi][ni] = __builtin_amdgcn_mfma_f32_16x16x32_bf16(af[mi], bfr[ni], acc[mi][ni], 0, 0, 0);
  }
  #pragma unroll
  for (int mi = 0; mi < 4; mi++)
    #pragma unroll
    for (int ni = 0; ni < 4; ni++) {
      const int n = n0 + wc * 64 + ni * 16 + fr;
      #pragma unroll
      for (int i = 0; i < 4; i++) {
        const float v = acc[mi][ni][i];
        const float vp = __shfl_xor(v, 1);
        if (!(fr & 1)) {
          const int m = row0 + wr * 64 + mi * 16 + g * 4 + i;
          abufp[(size_t)m * 1024 + (n >> 1)] = f2bf(siluf(v) * vp);
        }
      }
    }
}

// ---------------- packed MoE down GEMM ----------------
__global__ __launch_bounds__(256, 2) void gemm_moe_down(
    const u16* __restrict__ abuf, const u16* __restrict__ wDN,
    u16* __restrict__ dout, const float* __restrict__ gatew,
    const int* __restrict__ meta)
{
  const int by = blockIdx.y;
  if (by >= meta[24]) return;
  const int e = meta[32 + by];
  const int row0 = meta[104 + by];
  __shared__ u16 As[128 * 32];
  __shared__ u16 Bs[128 * 32];
  const int tid = threadIdx.x, lane = tid & 63;
  const int wid = tid >> 6, wr = wid >> 1, wc = wid & 1;
  const int n0 = blockIdx.x * 128;
  const int fr = lane & 15, g = lane >> 4;
  const int sl8 = swz_rd_sl8(fr, g);
  const f32x4 zero = {0.f, 0.f, 0.f, 0.f};
  f32x4 acc[4][4];
  #pragma unroll
  for (int i = 0; i < 4; i++)
    #pragma unroll
    for (int j = 0; j < 4; j++) acc[i][j] = zero;
  const int r4 = tid >> 2, c8 = swz_src_c8(tid);
  const u16* pA = abuf + (size_t)(row0 + r4) * 1024 + c8;
  const u16* pB = wDN + (size_t)e * 1024 * 2048 + (size_t)(n0 + r4) * 1024 + c8;
  const size_t rstepA = (size_t)64 * 1024;
  const int l0 = tid * 8;
  for (int k0 = 0; k0 < 1024; k0 += 32) {
    if (k0) __syncthreads();
    gll16(pA + k0,          &As[l0]);
    gll16(pA + k0 + rstepA, &As[2048 + l0]);
    gll16(pB + k0,          &Bs[l0]);
    gll16(pB + k0 + rstepA, &Bs[2048 + l0]);
    __syncthreads();
    bf16x8 af[4], bfr[4];
    #pragma unroll
    for (int mi = 0; mi < 4; mi++)
      af[mi] = *(const bf16x8*)&As[(wr * 64 + mi * 16 + fr) * 32 + sl8];
    #pragma unroll
    for (int ni = 0; ni < 4; ni++)
      bfr[ni] = *(const bf16x8*)&Bs[(wc * 64 + ni * 16 + fr) * 32 + sl8];
    #pragma unroll
    for (int mi = 0; mi < 4; mi++)
      #pragma unroll
      for (int ni = 0; ni < 4; ni++)
        acc[mi][ni] = __builtin_amdgcn_mfma_f32_16x16x32_bf16(af[mi], bfr[ni], acc[mi][ni], 0, 0, 0);
  }
  #pragma unroll
  for (int mi = 0; mi < 4; mi++)
    #pragma unroll
    for (int ni = 0; ni < 4; ni++) {
      const int n = n0 + wc * 64 + ni * 16 + fr;
      #pragma unroll
      for (int i = 0; i < 4; i++) {
        const int m = row0 + wr * 64 + mi * 16 + g * 4 + i;
        dout[(size_t)m * 2048 + n] = f2bf(acc[mi][ni][i] * gatew[m]);
      }
    }
}

// ---------------- fused causal conv+silu+split AND dt softplus ----------------
__global__ __launch_bounds__(256) void conv_silu_dt(
    const float* __restrict__ proj, const float* __restrict__ cw, const float* __restrict__ cb,
    const float* __restrict__ dt_bias,
    float* __restrict__ x, float* __restrict__ Bc, float* __restrict__ Cc,
    float* __restrict__ dt)
{
  const int c = blockIdx.x * 256 + threadIdx.x;
  const int s = blockIdx.y;
  if (c < CONVDIM) {
    const float4 w = *(const float4*)&cw[c * 4];
    float acc = cb[c];
    const float* pc = proj + (size_t)DINNER + c;
    if (s >= 3) acc += pc[(size_t)(s-3) * NPROJP] * w.x;
    if (s >= 2) acc += pc[(size_t)(s-2) * NPROJP] * w.y;
    if (s >= 1) acc += pc[(size_t)(s-1) * NPROJP] * w.z;
    acc += pc[(size_t)s * NPROJP] * w.w;
    const float v = siluf(acc);
    if (c < DINNER)                 x[(size_t)s * DINNER + c] = v;
    else if (c < DINNER + NSTATE)   Bc[(size_t)s * NSTATE + (c - DINNER)] = v;
    else                            Cc[(size_t)s * NSTATE + (c - DINNER - NSTATE)] = v;
  } else if (c < CONVDIM + 64) {
    const int h = c - CONVDIM;
    const float v = proj[(size_t)s * NPROJP + (DINNER + CONVDIM) + h] + dt_bias[h];
    dt[(size_t)s * 64 + h] = fmaxf(v, 0.f) + log1pf(__expf(-fabsf(v)));
  }
}

// ---------------- sequential-order cumsum of dA ----------------
__global__ __launch_bounds__(64) void ssd_cum_seq(
    const float* __restrict__ dt, const float* __restrict__ A_log,
    float* __restrict__ cum, float* __restrict__ cdec)
{
  const int c = blockIdx.x, h = threadIdx.x;
  const float A = -__expf(A_log[h]);
  float run = 0.f;
  float* co = cum + ((size_t)(c * 64 + h)) * 256;
  const float* dp = dt + (size_t)c * 256 * 64 + h;
  #pragma unroll 4
  for (int l = 0; l < 256; l++) {
    run += dp[(size_t)l * 64] * A;
    co[l] = run;
  }
  cdec[c * 64 + h] = __expf(run);
}

// ---------------- CBt ----------------
__global__ __launch_bounds__(256) void ssd_cb(
    const float* __restrict__ Cc, const float* __restrict__ Bc, float* __restrict__ CBt)
{
  const int c = blockIdx.y;
  const int lt = blockIdx.x >> 2, st = blockIdx.x & 3;
  if (st > lt) return;
  __shared__ float Cn[128][64];
  __shared__ float Bn[128][64];
  const int tid = threadIdx.x;
  #pragma unroll
  for (int rep = 0; rep < 8; rep++) {
    const int lin = rep * 1024 + tid * 4;
    const int r = lin >> 7, cc = lin & 127;
    float4 cv = *(const float4*)&Cc[((size_t)(c*256 + lt*64 + r)) * 128 + cc];
    float4 bv = *(const float4*)&Bc[((size_t)(c*256 + st*64 + r)) * 128 + cc];
    Cn[cc+0][r] = cv.x; Cn[cc+1][r] = cv.y; Cn[cc+2][r] = cv.z; Cn[cc+3][r] = cv.w;
    Bn[cc+0][r] = bv.x; Bn[cc+1][r] = bv.y; Bn[cc+2][r] = bv.z; Bn[cc+3][r] = bv.w;
  }
  __syncthreads();
  const int lb = (tid >> 4) * 4, sb = (tid & 15) * 4;
  float acc[4][4] = {};
  for (int n = 0; n < 128; n++) {
    float cv[4], bv[4];
    #pragma unroll
    for (int i = 0; i < 4; i++) { cv[i] = Cn[n][lb+i]; bv[i] = Bn[n][sb+i]; }
    #pragma unroll
    for (int i = 0; i < 4; i++)
      #pragma unroll
      for (int j = 0; j < 4; j++) acc[i][j] += cv[i] * bv[j];
  }
  #pragma unroll
  for (int is = 0; is < 4; is++) {
    const int sg = st*64 + sb + is;
    float4 o; o.x = acc[0][is]; o.y = acc[1][is]; o.z = acc[2][is]; o.w = acc[3][is];
    *(float4*)&CBt[((size_t)(c*256 + sg)) * 256 + lt*64 + lb] = o;
  }
}

// ---------------- chunk states via MFMA (hi/lo 3-term) ----------------
__global__ __launch_bounds__(256, 2) void ssd_states_mfma(
    const float* __restrict__ x, const float* __restrict__ Bc, const float* __restrict__ dt,
    const float* __restrict__ cum, float* __restrict__ states)
{
  const int c = blockIdx.x, h = blockIdx.y;
  const int tid = threadIdx.x, lane = tid & 63, w = tid >> 6;
  const int fr = lane & 15, g = lane >> 4;
  __shared__ float cd[256];
  __shared__ u16 Xth[64 * 32],  Xtl[64 * 32];
  __shared__ u16 Bth[128 * 32], Btl[128 * 32];
  {
    const float* cumh = cum + ((size_t)(c*64 + h)) * 256;
    cd[tid] = __expf(cumh[255] - cumh[tid]) * dt[(size_t)(c*256 + tid) * 64 + h];
  }
  const f32x4 zero = {0.f, 0.f, 0.f, 0.f};
  f32x4 acc[4][2];
  #pragma unroll
  for (int i = 0; i < 4; i++) { acc[i][0] = zero; acc[i][1] = zero; }
  for (int lt = 0; lt < 8; lt++) {
    __syncthreads();
    {
      const int ll = tid >> 3, p0 = (tid & 7) * 8;
      const int lg = c*256 + lt*32 + ll;
      const float cdv = cd[lt*32 + ll];
      const float* xr = x + (size_t)lg * DINNER + h*64 + p0;
      const float4 v0 = *(const float4*)&xr[0];
      const float4 v1 = *(const float4*)&xr[4];
      #pragma unroll
      for (int q = 0; q < 8; q++) {
        const float v = ((q < 4) ? ((const float*)&v0)[q] : ((const float*)&v1)[q-4]) * cdv;
        const u16 H = f2bf(v);
        Xth[(p0 + q) * 32 + ll] = H;
        Xtl[(p0 + q) * 32 + ll] = f2bf(v - bf2f(H));
      }
    }
    {
      const int ll = tid >> 3, n0 = (tid & 7) * 16;
      const float* br = Bc + (size_t)(c*256 + lt*32 + ll) * 128 + n0;
      #pragma unroll
      for (int q4 = 0; q4 < 4; q4++) {
        const float4 bv = *(const float4*)&br[q4*4];
        #pragma unroll
        for (int q = 0; q < 4; q++) {
          const float v = ((const float*)&bv)[q];
          const u16 H = f2bf(v);
          Bth[(n0 + q4*4 + q) * 32 + ll] = H;
          Btl[(n0 + q4*4 + q) * 32 + ll] = f2bf(v - bf2f(H));
        }
      }
    }
    __syncthreads();
    bf16x8 ah[4], al[4], bh[2], bl[2];
    #pragma unroll
    for (int mi = 0; mi < 4; mi++) {
      const int a = (mi*16 + fr) * 32 + g*8;
      ah[mi] = *(const bf16x8*)&Xth[a];
      al[mi] = *(const bf16x8*)&Xtl[a];
    }
    #pragma unroll
    for (int ni = 0; ni < 2; ni++) {
      const int b = (w*32 + ni*16 + fr) * 32 + g*8;
      bh[ni] = *(const bf16x8*)&Bth[b];
      bl[ni] = *(const bf16x8*)&Btl[b];
    }
    #pragma unroll
    for (int mi = 0; mi < 4; mi++)
      #pragma unroll
      for (int ni = 0; ni < 2; ni++) {
        acc[mi][ni] = __builtin_amdgcn_mfma_f32_16x16x32_bf16(al[mi], bh[ni], acc[mi][ni], 0, 0, 0);
        acc[mi][ni] = __builtin_amdgcn_mfma_f32_16x16x32_bf16(ah[mi], bl[ni], acc[mi][ni], 0, 0, 0);
        acc[mi][ni] = __builtin_amdgcn_mfma_f32_16x16x32_bf16(ah[mi], bh[ni], acc[mi][ni], 0, 0, 0);
      }
  }
  #pragma unroll
  for (int mi = 0; mi < 4; mi++)
    #pragma unroll
    for (int ni = 0; ni < 2; ni++)
      #pragma unroll
      for (int i = 0; i < 4; i++) {
        const int p = mi*16 + g*4 + i;
        const int n = w*32 + ni*16 + fr;
        states[(((size_t)(c*64 + h)) * 64 + p) * 128 + n] = acc[mi][ni][i];
      }
}

// ---------------- sequential scan over the 16 chunks ----------------
__global__ void ssd_scan(
    const float* __restrict__ states, const float* __restrict__ cdec, float* __restrict__ prev)
{
  const int hp = blockIdx.x;
  const int n = threadIdx.x;
  const int h = hp >> 6;
  float carry = 0.f;
  for (int c = 0; c < NCHUNK; c++) {
    const size_t idx = ((size_t)c * 4096 + hp) * 128 + n;
    prev[idx] = carry;
    carry = carry * cdec[c*64 + h] + states[idx];
  }
}

// ---------------- FUSED intra + inter Y via MFMA (3-term) + D*x + silu(z) gating ----------------
__global__ __launch_bounds__(256, 2) void ssd_intra_final_mfma(
    const float* __restrict__ x, const float* __restrict__ dt, const float* __restrict__ cum,
    const float* __restrict__ CBt, const float* __restrict__ Cc, const float* __restrict__ prev,
    const float* __restrict__ proj, const float* __restrict__ Dp, float* __restrict__ Yw)
{
  const int c = blockIdx.x, h = blockIdx.y;
  const int tid = threadIdx.x, lane = tid & 63, w = tid >> 6;
  const int fr = lane & 15, g = lane >> 4;
  __shared__ float cumL[256];
  __shared__ float odecL[256];
  __shared__ u16 Ph[256 * 32], Pl[256 * 32];   // phase2 reuse: Ch/Cl
  __shared__ u16 Xh[64 * 32],  Xl[64 * 32];    // phase2 reuse: Pvh/Pvl
  cumL[tid] = cum[((size_t)(c*64 + h)) * 256 + tid];
  odecL[tid] = __expf(cumL[tid]);
  const f32x4 zero = {0.f, 0.f, 0.f, 0.f};
  f32x4 acc[4][4];
  #pragma unroll
  for (int i = 0; i < 4; i++)
    #pragma unroll
    for (int j = 0; j < 4; j++) acc[i][j] = zero;
  const size_t cb0 = (size_t)c * 65536;
  // ---- phase 1: intra-chunk ----
  for (int ts = 0; ts < 8; ts++) {
    __syncthreads();
    {
      const int sl = tid >> 3, p0 = (tid & 7) * 8;
      const int sg = c*256 + ts*32 + sl;
      const float dtv = dt[(size_t)sg * 64 + h];
      const float* xr = x + (size_t)sg * DINNER + h*64 + p0;
      const float4 v0 = *(const float4*)&xr[0];
      const float4 v1 = *(const float4*)&xr[4];
      #pragma unroll
      for (int q = 0; q < 8; q++) {
        const float v = ((q < 4) ? ((const float*)&v0)[q] : ((const float*)&v1)[q-4]) * dtv;
        const u16 H = f2bf(v);
        Xh[(p0 + q) * 32 + sl] = H;
        Xl[(p0 + q) * 32 + sl] = f2bf(v - bf2f(H));
      }
    }
    {
      const int l = tid;
      const float myc = cumL[l];
      #pragma unroll 4
      for (int j = 0; j < 32; j++) {
        const int s = ts*32 + j;
        const float cb = CBt[cb0 + (size_t)s * 256 + l];
        float p = 0.f;
        if (s <= l) p = cb * __expf(myc - cumL[s]);
        const u16 H = f2bf(p);
        Ph[l * 32 + j] = H;
        Pl[l * 32 + j] = f2bf(p - bf2f(H));
      }
    }
    __syncthreads();
    if (ts * 32 < (w + 1) * 64) {
      bf16x8 ah[4], al[4], bh[4], bl[4];
      #pragma unroll
      for (int mi = 0; mi < 4; mi++) {
        const int a = (w*64 + mi*16 + fr) * 32 + g*8;
        ah[mi] = *(const bf16x8*)&Ph[a];
        al[mi] = *(const bf16x8*)&Pl[a];
      }
      #pragma unroll
      for (int ni = 0; ni < 4; ni++) {
        const int b = (ni*16 + fr) * 32 + g*8;
        bh[ni] = *(const bf16x8*)&Xh[b];
        bl[ni] = *(const bf16x8*)&Xl[b];
      }
      #pragma unroll
      for (int mi = 0; mi < 4; mi++)
        #pragma unroll
        for (int ni = 0; ni < 4; ni++) {
          acc[mi][ni] = __builtin_amdgcn_mfma_f32_16x16x32_bf16(al[mi], bh[ni], acc[mi][ni], 0, 0, 0);
          acc[mi][ni] = __builtin_amdgcn_mfma_f32_16x16x32_bf16(ah[mi], bl[ni], acc[mi][ni], 0, 0, 0);
          acc[mi][ni] = __builtin_amdgcn_mfma_f32_16x16x32_bf16(ah[mi], bh[ni], acc[mi][ni], 0, 0, 0);
        }
    }
  }
  // ---- phase 2: inter-chunk, C pre-scaled by odec ----
  for (int nt = 0; nt < 4; nt++) {
    __syncthreads();
    {
      #pragma unroll
      for (int rep = 0; rep < 32; rep++) {
        const int l = rep*8 + (tid >> 5);
        const int j = tid & 31;
        const float v = Cc[(size_t)(c*256 + l) * 128 + nt*32 + j] * odecL[l];
        const u16 H = f2bf(v);
        Ph[l*32 + j] = H;
        Pl[l*32 + j] = f2bf(v - bf2f(H));
      }
    }
    {
      const int p = tid >> 2, q0 = (tid & 3) * 8;
      const float* pr = prev + ((size_t)c * 4096 + h*64 + p) * 128 + nt*32 + q0;
      const float4 v0 = *(const float4*)&pr[0];
      const float4 v1 = *(const float4*)&pr[4];
      #pragma unroll
      for (int q = 0; q < 8; q++) {
        const float v = (q < 4) ? ((const float*)&v0)[q] : ((const float*)&v1)[q-4];
        const u16 H = f2bf(v);
        Xh[p*32 + q0 + q] = H;
        Xl[p*32 + q0 + q] = f2bf(v - bf2f(H));
      }
    }
    __syncthreads();
    bf16x8 ah[4], al[4], bh[4], bl[4];
    #pragma unroll
    for (int mi = 0; mi < 4; mi++) {
      const int a = (w*64 + mi*16 + fr) * 32 + g*8;
      ah[mi] = *(const bf16x8*)&Ph[a];
      al[mi] = *(const bf16x8*)&Pl[a];
    }
    #pragma unroll
    for (int ni = 0; ni < 4; ni++) {
      const int b = (ni*16 + fr) * 32 + g*8;
      bh[ni] = *(const bf16x8*)&Xh[b];
      bl[ni] = *(const bf16x8*)&Xl[b];
    }
    #pragma unroll
    for (int mi = 0; mi < 4; mi++)
      #pragma unroll
      for (int ni = 0; ni < 4; ni++) {
        acc[mi][ni] = __builtin_amdgcn_mfma_f32_16x16x32_bf16(al[mi], bh[ni], acc[mi][ni], 0, 0, 0);
        acc[mi][ni] = __builtin_amdgcn_mfma_f32_16x16x32_bf16(ah[mi], bl[ni], acc[mi][ni], 0, 0, 0);
        acc[mi][ni] = __builtin_amdgcn_mfma_f32_16x16x32_bf16(ah[mi], bh[ni], acc[mi][ni], 0, 0, 0);
      }
  }
  // ---- epilogue: +D*x, gate by silu(z), single Y write ----
  const float Dv = Dp[h];
  #pragma unroll
  for (int mi = 0; mi < 4; mi++) {
    #pragma unroll
    for (int i = 0; i < 4; i++) {
      const int l = w*64 + mi*16 + g*4 + i;
      const size_t rowo = (size_t)(c*256 + l);
      #pragma unroll
      for (int ni = 0; ni < 4; ni++) {
        const int p = ni*16 + fr;
        const size_t iy = rowo * DINNER + h*64 + p;
        const float yv = acc[mi][ni][i] + Dv * x[iy];
        const float z = proj[rowo * NPROJP + h*64 + p];
        Yw[iy] = yv * siluf(z);
      }
    }
  }
}

// ---------------- fused: rmsnorm(hidden2)->ht bf16 AND router top-2 ----------------
__global__ __launch_bounds__(256) void router_norm(
    const float* __restrict__ h2, const float* __restrict__ ln2w,
    const float* __restrict__ rw, u16* __restrict__ ht,
    int* __restrict__ eidx, float* __restrict__ ew)
{
  const int t = blockIdx.x;
  const float* xr = h2 + (size_t)t * DMODEL;
  float ss = 0.f;
  for (int i = threadIdx.x * 4; i < DMODEL; i += 1024) {
    float4 v = *(const float4*)&xr[i];
    ss += v.x*v.x + v.y*v.y + v.z*v.z + v.w*v.w;
  }
  #pragma unroll
  for (int off = 32; off > 0; off >>= 1) ss += __shfl_down(ss, off);
  __shared__ float red[4];
  if ((threadIdx.x & 63) == 0) red[threadIdx.x >> 6] = ss;
  __syncthreads();
  const float scale = rsqrtf((red[0]+red[1]+red[2]+red[3]) / (float)DMODEL + 1e-5f);
  float acc[8];
  #pragma unroll
  for (int j = 0; j < 8; j++) acc[j] = 0.f;
  u16* o = ht + (size_t)t * DMODEL;
  for (int i = threadIdx.x; i < DMODEL; i += 256) {
    const float v = xr[i] * scale * ln2w[i];
    o[i] = f2bf(v);
    const float* r = rw + (size_t)i * 8;
    #pragma unroll
    for (int j = 0; j < 8; j++) acc[j] += v * r[j];
  }
  #pragma unroll
  for (int j = 0; j < 8; j++)
    #pragma unroll
    for (int off = 32; off > 0; off >>= 1) acc[j] += __shfl_down(acc[j], off);
  __shared__ float rbuf[4][8];
  if ((threadIdx.x & 63) == 0)
    #pragma unroll
    for (int j = 0; j < 8; j++) rbuf[threadIdx.x >> 6][j] = acc[j];
  __syncthreads();
  if (threadIdx.x == 0) {
    float lg[8];
    #pragma unroll
    for (int j = 0; j < 8; j++) lg[j] = rbuf[0][j]+rbuf[1][j]+rbuf[2][j]+rbuf[3][j];
    int i1 = 0;
    #pragma unroll
    for (int j = 1; j < 8; j++) if (lg[j] > lg[i1]) i1 = j;
    int i2 = -1;
    #pragma unroll
    for (int j = 0; j < 8; j++) if (j != i1 && (i2 < 0 || lg[j] > lg[i2])) i2 = j;
    const float e2 = __expf(lg[i2] - lg[i1]);
    const float inv = 1.f / (1.f + e2);
    eidx[t*2]   = i1;  ew[t*2]   = inv;
    eidx[t*2+1] = i2;  ew[t*2+1] = e2 * inv;
  }
}

// ---------------- single-block MoE routing: zero + count + offsets + place ----------------
__global__ __launch_bounds__(1024) void moe_route(
    const int* __restrict__ eidx, const float* __restrict__ ew,
    int* __restrict__ tokmap, float* __restrict__ gatew,
    int* __restrict__ posmap, int* __restrict__ meta)
{
  const int tid = threadIdx.x;
  __shared__ int cnt[8], base[8];
  if (tid < 8) cnt[tid] = 0;
  for (int i = tid; i < MAXROWS; i += 1024) tokmap[i] = 0;
  __syncthreads();
  for (int i = tid; i < SEQ * 2; i += 1024)
    atomicAdd(&cnt[eidx[i]], 1);
  __syncthreads();
  if (tid == 0) {
    int off = 0, T = 0;
    for (int e = 0; e < 8; e++) {
      base[e] = off;
      meta[16 + e] = off;
      const int nt = (cnt[e] + 127) >> 7;
      for (int j = 0; j < nt; j++) {
        meta[32 + T] = e;
        meta[104 + T] = off + j * 128;
        T++;
      }
      off += nt * 128;
      cnt[e] = 0;
    }
    meta[24] = T;
  }
  __syncthreads();
  for (int i = tid; i < SEQ * 2; i += 1024) {
    const int e = eidx[i];
    const int pos = atomicAdd(&cnt[e], 1);
    const int r = base[e] + pos;
    tokmap[r] = i >> 1;
    gatew[r] = ew[i];
    posmap[i] = r;
  }
}

// ---------------- out0 = h2 + RESM*(shared + dout[pos0] + dout[pos1]) ----------------
__global__ __launch_bounds__(256) void final_moe(
    const float* __restrict__ h2, const float* __restrict__ shout,
    const u16* __restrict__ dout, const int* __restrict__ posmap,
    float* __restrict__ o)
{
  const int t = blockIdx.x;
  const int p0 = posmap[t*2], p1 = posmap[t*2+1];
  const u16* d0 = dout + (size_t)p0 * 2048 + threadIdx.x * 8;
  const u16* d1 = dout + (size_t)p1 * 2048 + threadIdx.x * 8;
  const size_t base = (size_t)t * 2048 + threadIdx.x * 8;
  #pragma unroll
  for (int q = 0; q < 8; q++) {
    const float ff = shout[base + q] + bf2f(d0[q]) + bf2f(d1[q]);
    o[base + q] = h2[base + q] + RESM * ff;
  }
}

// ---------------- workspace layout (bytes) ----------------
#define OFF_WAH   ((size_t)0)
#define OFF_WAL   ((size_t)35127296)
#define OFF_PROJ  ((size_t)70254592)
#define OFF_X     ((size_t)210763776)
#define OFF_Y     ((size_t)277872640)
#define OFF_HP    ((size_t)344981504)
#define OFF_BC    ((size_t)378535936)
#define OFF_CC    ((size_t)380633088)
#define OFF_DT    ((size_t)382730240)
#define OFF_CUM   ((size_t)383778816)
#define OFF_CDEC  ((size_t)384827392)
#define OFF_CB    ((size_t)384831488)

extern "C" void kernel_launch(void* const* d_in, const int* in_sizes, int n_in,
                              void* d_out, int out_size, void* d_ws, size_t ws_size,
                              hipStream_t stream)
{
  const float* hs       = (const float*)d_in[1];
  const float* ln1_w    = (const float*)d_in[2];
  const float* w_inproj = (const float*)d_in[3];
  const float* conv_w   = (const float*)d_in[4];
  const float* conv_b   = (const float*)d_in[5];
  const float* A_log    = (const float*)d_in[6];
  const float* dt_bias  = (const float*)d_in[7];
  const float* D_param  = (const float*)d_in[8];
  const float* mnorm_w  = (const float*)d_in[9];
  const float* w_outp   = (const float*)d_in[10];
  const float* ln2_w    = (const float*)d_in[11];
  const float* router_w = (const float*)d_in[12];
  const float* w_gu     = (const float*)d_in[13];
  const float* w_down   = (const float*)d_in[14];
  const float* w_shin   = (const float*)d_in[15];
  const float* w_shout  = (const float*)d_in[16];

  char* ws = (char*)d_ws;
  u16*   wAh    = (u16*)(ws + OFF_WAH);
  u16*   wAl    = (u16*)(ws + OFF_WAL);
  float* projf  = (float*)(ws + OFF_PROJ);
  float* xbuf   = (float*)(ws + OFF_X);
  float* ybuf   = (float*)(ws + OFF_Y);
  float* Bcb    = (float*)(ws + OFF_BC);
  float* Ccb    = (float*)(ws + OFF_CC);
  float* dtb    = (float*)(ws + OFF_DT);
  float* cumb   = (float*)(ws + OFF_CUM);
  float* cdecb  = (float*)(ws + OFF_CDEC);
  float* cbt    = (float*)(ws + OFF_CB);

  // lifetime-overlapped aliases
  u16*   hhi    = (u16*)(ws + OFF_HP);
  u16*   hlo    = (u16*)(ws + OFF_HP + 16777216);
  float* prevb  = (float*)(ws + OFF_HP);
  u16*   wDN    = (u16*)(ws + OFF_HP);                   // 32MiB after prev dead
  float* stbuf  = (float*)(ws + OFF_WAH);
  u16*   ynhi   = (u16*)(ws + OFF_WAH);
  u16*   ynlo   = (u16*)(ws + OFF_WAL);
  u16*   wBh    = (u16*)(ws + OFF_PROJ);
  u16*   wBl    = (u16*)(ws + OFF_PROJ + 16777216);
  u16*   wE     = (u16*)(ws + OFF_WAH);                  // shared-in Wt interleaved (33.5M)
  u16*   wD     = (u16*)(ws + OFF_WAH + 33554432);       // shared-out Wt (16.8M)
  u16*   wGU    = (u16*)(ws + OFF_WAH);                  // expert gate_up Wt interleaved (64M)
  u16*   abufp  = (u16*)(ws + OFF_PROJ + 83886080);      // packed a bf16 (18.9M)
  u16*   ht     = (u16*)(ws + OFF_X);
  u16*   ash    = (u16*)(ws + OFF_X + 16777216);         // shared a bf16 (33.5M)
  u16*   dout   = (u16*)(ws + OFF_X + 16777216);         // packed dout bf16, after ash dead
  float* shout  = (float*)(ws + OFF_Y);

  int*   eidx   = (int*)(ws + OFF_BC);
  float* ew     = (float*)(ws + OFF_BC + 65536);
  int*   posmap = (int*)(ws + OFF_BC + 131072);
  int*   tokmap = (int*)(ws + OFF_BC + 196608);
  float* gatew  = (float*)(ws + OFF_BC + 262144);
  int*   meta   = (int*)(ws + OFF_BC + 327680);

  float* out0    = (float*)d_out;
  float* hidden2 = out0 + (size_t)SEQ * DMODEL;

  // ---- Mamba block ----
  rmsnorm_split<<<SEQ, 256, 0, stream>>>(hs, ln1_w, hhi, hlo, DMODEL);
  wconv_t_split<<<dim3(NPROJ/32, DMODEL/32), 256, 0, stream>>>(w_inproj, wAh, wAl, DMODEL, NPROJ);
  gemm_dd<3><<<67*32, 256, 0, stream>>>(hhi, hlo, wAh, wAl, projf, nullptr,
                                        NPROJ, DMODEL, NPROJP, 0.f, 67, 32, 4);
  conv_silu_dt<<<dim3(18, SEQ), 256, 0, stream>>>(projf, conv_w, conv_b, dt_bias,
                                                  xbuf, Bcb, Ccb, dtb);
  ssd_cum_seq<<<NCHUNK, 64, 0, stream>>>(dtb, A_log, cumb, cdecb);
  ssd_cb<<<dim3(16, NCHUNK), 256, 0, stream>>>(Ccb, Bcb, cbt);
  ssd_states_mfma<<<dim3(NCHUNK, NHEADS), 256, 0, stream>>>(xbuf, Bcb, dtb, cumb, stbuf);
  ssd_scan<<<NHEADS*HEADP, 128, 0, stream>>>(stbuf, cdecb, prevb);
  ssd_intra_final_mfma<<<dim3(NCHUNK, NHEADS), 256, 0, stream>>>(
      xbuf, dtb, cumb, cbt, Ccb, prevb, projf, D_param, ybuf);
  rmsnorm_split<<<SEQ, 256, 0, stream>>>(ybuf, mnorm_w, ynhi, ynlo, DINNER);
  wconv_t_split<<<dim3(DMODEL/32, DINNER/32), 256, 0, stream>>>(w_outp, wBh, wBl, DINNER, DMODEL);
  gemm_dd<1><<<16*32, 256, 0, stream>>>(ynhi, ynlo, wBh, wBl, hidden2, hs,
                                        DMODEL, DINNER, DMODEL, RESM, 16, 32, 4);

  // ---- Router + ht norm (fused) + single-kernel token packing ----
  router_norm<<<SEQ, 256, 0, stream>>>(hidden2, ln2_w, router_w, ht, eidx, ew);
  moe_route<<<1, 1024, 0, stream>>>(eidx, ew, tokmap, gatew, posmap, meta);

  // ---- Shared expert (dense, GLU fused into gate_up GEMM) ----
  wconv_t_glu<<<dim3(8192/32, DMODEL/32), 256, 0, stream>>>(w_shin, wE, DMODEL, 8192, 4096);
  gemm_bt_glu<<<64*32, 256, 0, stream>>>(ht, wE, ash, DMODEL, 4096, 64, 32, 4);
  wconv_t<<<dim3(DMODEL/32, 4096/32), 256, 0, stream>>>(w_shout, wD, 4096, DMODEL);
  gemm_bt<3><<<16*32, 256, 0, stream>>>(ash, wD, shout, DMODEL, 4096, DMODEL, 16, 32, 4);

  // ---- Sparse top-2 experts (packed, GLU fused) ----
  wconv_t_glu<<<dim3(2048/32, DMODEL/32, 8), 256, 0, stream>>>(w_gu, wGU, DMODEL, 2048, 1024);
  wconv_t<<<dim3(DMODEL/32, 1024/32, 8), 256, 0, stream>>>(w_down, wDN, 1024, DMODEL);
  gemm_moe_gu<<<dim3(16, MAXTILE), 256, 0, stream>>>(ht, wGU, abufp, tokmap, meta);
  gemm_moe_down<<<dim3(16, MAXTILE), 256, 0, stream>>>(abufp, wDN, dout, gatew, meta);

  final_moe<<<SEQ, 256, 0, stream>>>(hidden2, shout, dout, posmap, out0);
}

// Round 14
// 1722.495 us; speedup vs baseline: 1.0662x; 1.0231x over previous
//
#include <hip/hip_runtime.h>
#include <stdint.h>

typedef unsigned short u16;
typedef __attribute__((ext_vector_type(8))) __bf16 bf16x8;
typedef __attribute__((ext_vector_type(4))) float f32x4;

#define SEQ     4096
#define DMODEL  2048
#define DINNER  4096
#define NHEADS  64
#define HEADP   64
#define NSTATE  128
#define NCHUNK  16
#define CHUNKL  256
#define NPROJ   8512
#define NPROJP  8576
#define CONVDIM 4352
#define RESM    0.22f
#define MAXROWS 9216
#define MAXTILE 72

static __device__ __forceinline__ u16 f2bf(float f){
  union { float f; uint32_t u; } v; v.f = f;
  uint32_t r = v.u + 0x7fffu + ((v.u >> 16) & 1u);
  return (u16)(r >> 16);
}
static __device__ __forceinline__ float bf2f(u16 h){
  union { uint32_t u; float f; } v; v.u = ((uint32_t)h) << 16;
  return v.f;
}
static __device__ __forceinline__ float siluf(float x){ return x / (1.f + __expf(-x)); }

// async global->LDS, 16B per lane
static __device__ __forceinline__ void gll16(const void* g, void* l) {
  __builtin_amdgcn_global_load_lds(
      (const __attribute__((address_space(1))) void*)g,
      (__attribute__((address_space(3))) void*)l, 16, 0, 0);
}

// LDS bank-conflict swizzle (free; conflicts measured 0 since r8)
static __device__ __forceinline__ int swz_src_c8(int tid) {
  return ((((tid & 3) - ((tid >> 3) & 3) + 4) & 3) * 8);
}
static __device__ __forceinline__ int swz_rd_sl8(int fr, int g) {
  return (((g + ((fr >> 1) & 3)) & 3) * 8);
}

// XCD-chunked bijective swizzle + G-column L2 grouping (nwg % 8 == 0 for all users).
static __device__ __forceinline__ void decode_tile(
    int id, int NB, int MB, int G, int& bx, int& by)
{
  const int nwg = NB * MB;
  int sid = id;
  if (!(nwg & 7)) {
    const int cpx = nwg >> 3;
    sid = (id & 7) * cpx + (id >> 3);
  }
  const int gsz = MB * G;
  const int fullG = NB / G;
  const int fullCnt = fullG * gsz;
  if (sid < fullCnt) {
    const int grp = sid / gsz;
    const int r = sid - grp * gsz;
    const int q = r / G;
    by = q;
    bx = grp * G + (r - q * G);
  } else {
    const int rem = NB - fullG * G;
    const int r = sid - fullCnt;
    const int q = r / rem;
    by = q;
    bx = fullG * G + (r - q * rem);
  }
}

// ---------------- rmsnorm: f32 in -> bf16 hi+lo split ----------------
__global__ __launch_bounds__(256) void rmsnorm_split(
    const float* __restrict__ in, const float* __restrict__ w,
    u16* __restrict__ hi, u16* __restrict__ lo, int width)
{
  const int row = blockIdx.x;
  const float* x = in + (size_t)row * width;
  float ss = 0.f;
  for (int i = threadIdx.x * 4; i < width; i += 1024) {
    float4 v = *(const float4*)&x[i];
    ss += v.x*v.x + v.y*v.y + v.z*v.z + v.w*v.w;
  }
  #pragma unroll
  for (int off = 32; off > 0; off >>= 1) ss += __shfl_down(ss, off);
  __shared__ float red[4];
  if ((threadIdx.x & 63) == 0) red[threadIdx.x >> 6] = ss;
  __syncthreads();
  const float total = red[0] + red[1] + red[2] + red[3];
  const float scale = rsqrtf(total / (float)width + 1e-5f);
  u16* oh = hi + (size_t)row * width;
  u16* ol = lo + (size_t)row * width;
  for (int i = threadIdx.x * 4; i < width; i += 1024) {
    float4 v = *(const float4*)&x[i];
    float4 g = *(const float4*)&w[i];
    #pragma unroll
    for (int q = 0; q < 4; q++) {
      const float val = ((const float*)&v)[q] * scale * ((const float*)&g)[q];
      const u16 H = f2bf(val);
      oh[i+q] = H;
      ol[i+q] = f2bf(val - bf2f(H));
    }
  }
}

// ---------- weight convert+transpose: W (K x N) f32 -> Bt (N x K) bf16 ----------
__global__ __launch_bounds__(256) void wconv_t(
    const float* __restrict__ W, u16* __restrict__ Bt, int K, int N)
{
  const size_t eo = (size_t)blockIdx.z * K * N;
  W += eo; Bt += eo;
  __shared__ float t[32][33];
  const int n0 = blockIdx.x * 32, k0 = blockIdx.y * 32;
  const int tx = threadIdx.x & 31, ty = threadIdx.x >> 5;
  #pragma unroll
  for (int r = 0; r < 32; r += 8)
    t[ty + r][tx] = W[(size_t)(k0 + ty + r) * N + n0 + tx];
  __syncthreads();
  #pragma unroll
  for (int r = 0; r < 32; r += 8)
    Bt[(size_t)(n0 + ty + r) * K + k0 + tx] = f2bf(t[tx][ty + r]);
}

// ---------- weight convert+transpose with gate/up column interleave ----------
__global__ __launch_bounds__(256) void wconv_t_glu(
    const float* __restrict__ W, u16* __restrict__ Bt, int K, int N, int H)
{
  const size_t eo = (size_t)blockIdx.z * K * N;
  W += eo; Bt += eo;
  __shared__ float t[32][33];
  const int n0 = blockIdx.x * 32, k0 = blockIdx.y * 32;
  const int tx = threadIdx.x & 31, ty = threadIdx.x >> 5;
  #pragma unroll
  for (int r = 0; r < 32; r += 8)
    t[ty + r][tx] = W[(size_t)(k0 + ty + r) * N + n0 + tx];
  __syncthreads();
  #pragma unroll
  for (int r = 0; r < 32; r += 8) {
    const int n = n0 + ty + r;
    const int orow = (n < H) ? (2 * n) : (2 * (n - H) + 1);
    Bt[(size_t)orow * K + k0 + tx] = f2bf(t[tx][ty + r]);
  }
}

// ---------- weight convert+transpose with hi/lo split ----------
__global__ __launch_bounds__(256) void wconv_t_split(
    const float* __restrict__ W, u16* __restrict__ Bth, u16* __restrict__ Btl, int K, int N)
{
  __shared__ float t[32][33];
  const int n0 = blockIdx.x * 32, k0 = blockIdx.y * 32;
  const int tx = threadIdx.x & 31, ty = threadIdx.x >> 5;
  #pragma unroll
  for (int r = 0; r < 32; r += 8)
    t[ty + r][tx] = W[(size_t)(k0 + ty + r) * N + n0 + tx];
  __syncthreads();
  #pragma unroll
  for (int r = 0; r < 32; r += 8) {
    const float val = t[tx][ty + r];
    const u16 H = f2bf(val);
    const size_t idx = (size_t)(n0 + ty + r) * K + k0 + tx;
    Bth[idx] = H;
    Btl[idx] = f2bf(val - bf2f(H));
  }
}

// ---------------- GEMM: C[M,N] = A[M,K] * Bt[N,K]^T, EPI 3: C f32 = acc ----------------
template<int EPI>
__global__ __launch_bounds__(256, 2) void gemm_bt(
    const u16* __restrict__ A, const u16* __restrict__ Bt,
    float* __restrict__ Cf,
    int Nreal, int K, int ldc, int NB, int MB, int G)
{
  __shared__ u16 As[128 * 32];
  __shared__ u16 Bs[128 * 32];
  int bx, by; decode_tile(blockIdx.x, NB, MB, G, bx, by);
  const int tid = threadIdx.x, lane = tid & 63;
  const int wid = tid >> 6, wr = wid >> 1, wc = wid & 1;
  const int m0 = by * 128, n0 = bx * 128;
  const int fr = lane & 15, g = lane >> 4;
  const int sl8 = swz_rd_sl8(fr, g);
  const f32x4 zero = {0.f, 0.f, 0.f, 0.f};
  f32x4 acc[4][4];
  #pragma unroll
  for (int i = 0; i < 4; i++)
    #pragma unroll
    for (int j = 0; j < 4; j++) acc[i][j] = zero;
  const int c8 = swz_src_c8(tid);
  const u16* pA = A  + (size_t)(m0 + (tid >> 2)) * K + c8;
  const u16* pB = Bt + (size_t)(n0 + (tid >> 2)) * K + c8;
  const size_t rstep = (size_t)64 * K;
  const int l0 = tid * 8;
  for (int k0 = 0; k0 < K; k0 += 32) {
    if (k0) __syncthreads();
    gll16(pA + k0,         &As[l0]);
    gll16(pA + k0 + rstep, &As[2048 + l0]);
    gll16(pB + k0,         &Bs[l0]);
    gll16(pB + k0 + rstep, &Bs[2048 + l0]);
    __syncthreads();
    bf16x8 af[4], bfr[4];
    #pragma unroll
    for (int mi = 0; mi < 4; mi++)
      af[mi] = *(const bf16x8*)&As[(wr * 64 + mi * 16 + fr) * 32 + sl8];
    #pragma unroll
    for (int ni = 0; ni < 4; ni++)
      bfr[ni] = *(const bf16x8*)&Bs[(wc * 64 + ni * 16 + fr) * 32 + sl8];
    #pragma unroll
    for (int mi = 0; mi < 4; mi++)
      #pragma unroll
      for (int ni = 0; ni < 4; ni++)
        acc[mi][ni] = __builtin_amdgcn_mfma_f32_16x16x32_bf16(af[mi], bfr[ni], acc[mi][ni], 0, 0, 0);
  }
  #pragma unroll
  for (int mi = 0; mi < 4; mi++) {
    #pragma unroll
    for (int ni = 0; ni < 4; ni++) {
      const int n = n0 + wc * 64 + ni * 16 + fr;
      if (n >= Nreal) continue;
      #pragma unroll
      for (int i = 0; i < 4; i++) {
        const int m = m0 + wr * 64 + mi * 16 + g * 4 + i;
        Cf[(size_t)m * ldc + n] = acc[mi][ni][i];
      }
    }
  }
}

// ---------------- GEMM with fused GLU epilogue (interleaved B) ----------------
__global__ __launch_bounds__(256, 2) void gemm_bt_glu(
    const u16* __restrict__ A, const u16* __restrict__ Bt,
    u16* __restrict__ aout,
    int K, int Nhalf, int NB, int MB, int G)
{
  __shared__ u16 As[128 * 32];
  __shared__ u16 Bs[128 * 32];
  int bx, by; decode_tile(blockIdx.x, NB, MB, G, bx, by);
  const int tid = threadIdx.x, lane = tid & 63;
  const int wid = tid >> 6, wr = wid >> 1, wc = wid & 1;
  const int m0 = by * 128, n0 = bx * 128;
  const int fr = lane & 15, g = lane >> 4;
  const int sl8 = swz_rd_sl8(fr, g);
  const f32x4 zero = {0.f, 0.f, 0.f, 0.f};
  f32x4 acc[4][4];
  #pragma unroll
  for (int i = 0; i < 4; i++)
    #pragma unroll
    for (int j = 0; j < 4; j++) acc[i][j] = zero;
  const int c8 = swz_src_c8(tid);
  const u16* pA = A  + (size_t)(m0 + (tid >> 2)) * K + c8;
  const u16* pB = Bt + (size_t)(n0 + (tid >> 2)) * K + c8;
  const size_t rstep = (size_t)64 * K;
  const int l0 = tid * 8;
  for (int k0 = 0; k0 < K; k0 += 32) {
    if (k0) __syncthreads();
    gll16(pA + k0,         &As[l0]);
    gll16(pA + k0 + rstep, &As[2048 + l0]);
    gll16(pB + k0,         &Bs[l0]);
    gll16(pB + k0 + rstep, &Bs[2048 + l0]);
    __syncthreads();
    bf16x8 af[4], bfr[4];
    #pragma unroll
    for (int mi = 0; mi < 4; mi++)
      af[mi] = *(const bf16x8*)&As[(wr * 64 + mi * 16 + fr) * 32 + sl8];
    #pragma unroll
    for (int ni = 0; ni < 4; ni++)
      bfr[ni] = *(const bf16x8*)&Bs[(wc * 64 + ni * 16 + fr) * 32 + sl8];
    #pragma unroll
    for (int mi = 0; mi < 4; mi++)
      #pragma unroll
      for (int ni = 0; ni < 4; ni++)
        acc[mi][ni] = __builtin_amdgcn_mfma_f32_16x16x32_bf16(af[mi], bfr[ni], acc[mi][ni], 0, 0, 0);
  }
  #pragma unroll
  for (int mi = 0; mi < 4; mi++) {
    #pragma unroll
    for (int ni = 0; ni < 4; ni++) {
      const int n = n0 + wc * 64 + ni * 16 + fr;
      #pragma unroll
      for (int i = 0; i < 4; i++) {
        const float v = acc[mi][ni][i];
        const float vp = __shfl_xor(v, 1);
        if (!(fr & 1)) {
          const int m = m0 + wr * 64 + mi * 16 + g * 4 + i;
          aout[(size_t)m * Nhalf + (n >> 1)] = f2bf(siluf(v) * vp);
        }
      }
    }
  }
}

// ---------------- double-bf16 GEMM: 3-term (hh + hl + lh), 16x16x32 ----------------
// EPI 1: C f32 = res + alpha*acc ; EPI 3: C f32 = acc
template<int EPI>
__global__ __launch_bounds__(256, 2) void gemm_dd(
    const u16* __restrict__ Ah, const u16* __restrict__ Al,
    const u16* __restrict__ Bh, const u16* __restrict__ Bl,
    float* __restrict__ Cf, const float* __restrict__ res,
    int Nreal, int K, int ldc, float alpha, int NB, int MB, int G)
{
  __shared__ u16 Ash[128 * 32];
  __shared__ u16 Asl[128 * 32];
  __shared__ u16 Bsh[128 * 32];
  __shared__ u16 Bsl[128 * 32];
  int bx, by; decode_tile(blockIdx.x, NB, MB, G, bx, by);
  const int tid = threadIdx.x, lane = tid & 63;
  const int wid = tid >> 6, wr = wid >> 1, wc = wid & 1;
  const int m0 = by * 128, n0 = bx * 128;
  const int fr = lane & 15, g = lane >> 4;
  const int sl8 = swz_rd_sl8(fr, g);
  const f32x4 zero = {0.f, 0.f, 0.f, 0.f};
  f32x4 acc[4][4];
  #pragma unroll
  for (int i = 0; i < 4; i++)
    #pragma unroll
    for (int j = 0; j < 4; j++) acc[i][j] = zero;
  const int c8 = swz_src_c8(tid);
  const size_t offA = (size_t)(m0 + (tid >> 2)) * K + c8;
  const size_t offB = (size_t)(n0 + (tid >> 2)) * K + c8;
  const size_t rstep = (size_t)64 * K;
  const int l0 = tid * 8;
  for (int k0 = 0; k0 < K; k0 += 32) {
    if (k0) __syncthreads();
    gll16(Ah + offA + k0,         &Ash[l0]);
    gll16(Ah + offA + k0 + rstep, &Ash[2048 + l0]);
    gll16(Al + offA + k0,         &Asl[l0]);
    gll16(Al + offA + k0 + rstep, &Asl[2048 + l0]);
    gll16(Bh + offB + k0,         &Bsh[l0]);
    gll16(Bh + offB + k0 + rstep, &Bsh[2048 + l0]);
    gll16(Bl + offB + k0,         &Bsl[l0]);
    gll16(Bl + offB + k0 + rstep, &Bsl[2048 + l0]);
    __syncthreads();
    bf16x8 ah[4], al[4], bh[4], bl[4];
    #pragma unroll
    for (int mi = 0; mi < 4; mi++) {
      const int a = (wr * 64 + mi * 16 + fr) * 32 + sl8;
      ah[mi] = *(const bf16x8*)&Ash[a];
      al[mi] = *(const bf16x8*)&Asl[a];
    }
    #pragma unroll
    for (int ni = 0; ni < 4; ni++) {
      const int b = (wc * 64 + ni * 16 + fr) * 32 + sl8;
      bh[ni] = *(const bf16x8*)&Bsh[b];
      bl[ni] = *(const bf16x8*)&Bsl[b];
    }
    #pragma unroll
    for (int mi = 0; mi < 4; mi++)
      #pragma unroll
      for (int ni = 0; ni < 4; ni++) {
        acc[mi][ni] = __builtin_amdgcn_mfma_f32_16x16x32_bf16(al[mi], bh[ni], acc[mi][ni], 0, 0, 0);
        acc[mi][ni] = __builtin_amdgcn_mfma_f32_16x16x32_bf16(ah[mi], bl[ni], acc[mi][ni], 0, 0, 0);
        acc[mi][ni] = __builtin_amdgcn_mfma_f32_16x16x32_bf16(ah[mi], bh[ni], acc[mi][ni], 0, 0, 0);
      }
  }
  #pragma unroll
  for (int mi = 0; mi < 4; mi++) {
    #pragma unroll
    for (int ni = 0; ni < 4; ni++) {
      const int n = n0 + wc * 64 + ni * 16 + fr;
      if (n >= Nreal) continue;
      #pragma unroll
      for (int i = 0; i < 4; i++) {
        const int m = m0 + wr * 64 + mi * 16 + g * 4 + i;
        const float v = acc[mi][ni][i];
        const size_t idx = (size_t)m * ldc + n;
        if constexpr (EPI == 1) {
          Cf[idx] = res[idx] + alpha * v;
        } else {
          Cf[idx] = v;
        }
      }
    }
  }
}

// ---------------- packed MoE gate_up GEMM + fused GLU (interleaved wGU) ----------------
__global__ __launch_bounds__(256, 2) void gemm_moe_gu(
    const u16* __restrict__ ht, const u16* __restrict__ wGU,
    u16* __restrict__ abufp, const int* __restrict__ tokmap,
    const int* __restrict__ meta)
{
  const int by = blockIdx.y;
  if (by >= meta[24]) return;
  const int e = meta[32 + by];
  const int row0 = meta[104 + by];
  __shared__ u16 As[128 * 32];
  __shared__ u16 Bs[128 * 32];
  const int tid = threadIdx.x, lane = tid & 63;
  const int wid = tid >> 6, wr = wid >> 1, wc = wid & 1;
  const int n0 = blockIdx.x * 128;
  const int fr = lane & 15, g = lane >> 4;
  const int sl8 = swz_rd_sl8(fr, g);
  const f32x4 zero = {0.f, 0.f, 0.f, 0.f};
  f32x4 acc[4][4];
  #pragma unroll
  for (int i = 0; i < 4; i++)
    #pragma unroll
    for (int j = 0; j < 4; j++) acc[i][j] = zero;
  const int r4 = tid >> 2, c8 = swz_src_c8(tid);
  const int tok0 = tokmap[row0 + r4];
  const int tok1 = tokmap[row0 + 64 + r4];
  const u16* pA0 = ht + (size_t)tok0 * DMODEL + c8;
  const u16* pA1 = ht + (size_t)tok1 * DMODEL + c8;
  const u16* pB  = wGU + (size_t)e * 2048 * DMODEL + (size_t)(n0 + r4) * DMODEL + c8;
  const size_t rstep = (size_t)64 * DMODEL;
  const int l0 = tid * 8;
  for (int k0 = 0; k0 < DMODEL; k0 += 32) {
    if (k0) __syncthreads();
    gll16(pA0 + k0,        &As[l0]);
    gll16(pA1 + k0,        &As[2048 + l0]);
    gll16(pB + k0,         &Bs[l0]);
    gll16(pB + k0 + rstep, &Bs[2048 + l0]);
    __syncthreads();
    bf16x8 af[4], bfr[4];
    #pragma unroll
    for (int mi = 0; mi < 4; mi++)
      af[mi] = *(const bf16x8*)&As[(wr * 64 + mi * 16 + fr) * 32 + sl8];
    #pragma unroll
    for (int ni = 0; ni < 4; ni++)
      bfr[ni] = *(const bf16x8*)&Bs[(wc * 64 + ni * 16 + fr) * 32 + sl8];
    #pragma unroll
    for (int mi = 0; mi < 4; mi++)
      #pragma unroll
      for (int ni = 0; ni < 4; ni++)
        acc[mi][ni] = __builtin_amdgcn_mfma_f32_16x16x32_bf16(af[mi], bfr[ni], acc[mi][ni], 0, 0, 0);
  }
  #pragma unroll
  for (int mi = 0; mi < 4; mi++)
    #pragma unroll
    for (int ni = 0; ni < 4; ni++) {
      const int n = n0 + wc * 64 + ni * 16 + fr;
      #pragma unroll
      for (int i = 0; i < 4; i++) {
        const float v = acc[mi][ni][i];
        const float vp = __shfl_xor(v, 1);
        if (!(fr & 1)) {
          const int m = row0 + wr * 64 + mi * 16 + g * 4 + i;
          abufp[(size_t)m * 1024 + (n >> 1)] = f2bf(siluf(v) * vp);
        }
      }
    }
}

// ---------------- packed MoE down GEMM ----------------
__global__ __launch_bounds__(256, 2) void gemm_moe_down(
    const u16* __restrict__ abuf, const u16* __restrict__ wDN,
    u16* __restrict__ dout, const float* __restrict__ gatew,
    const int* __restrict__ meta)
{
  const int by = blockIdx.y;
  if (by >= meta[24]) return;
  const int e = meta[32 + by];
  const int row0 = meta[104 + by];
  __shared__ u16 As[128 * 32];
  __shared__ u16 Bs[128 * 32];
  const int tid = threadIdx.x, lane = tid & 63;
  const int wid = tid >> 6, wr = wid >> 1, wc = wid & 1;
  const int n0 = blockIdx.x * 128;
  const int fr = lane & 15, g = lane >> 4;
  const int sl8 = swz_rd_sl8(fr, g);
  const f32x4 zero = {0.f, 0.f, 0.f, 0.f};
  f32x4 acc[4][4];
  #pragma unroll
  for (int i = 0; i < 4; i++)
    #pragma unroll
    for (int j = 0; j < 4; j++) acc[i][j] = zero;
  const int r4 = tid >> 2, c8 = swz_src_c8(tid);
  const u16* pA = abuf + (size_t)(row0 + r4) * 1024 + c8;
  const u16* pB = wDN + (size_t)e * 1024 * 2048 + (size_t)(n0 + r4) * 1024 + c8;
  const size_t rstepA = (size_t)64 * 1024;
  const int l0 = tid * 8;
  for (int k0 = 0; k0 < 1024; k0 += 32) {
    if (k0) __syncthreads();
    gll16(pA + k0,          &As[l0]);
    gll16(pA + k0 + rstepA, &As[2048 + l0]);
    gll16(pB + k0,          &Bs[l0]);
    gll16(pB + k0 + rstepA, &Bs[2048 + l0]);
    __syncthreads();
    bf16x8 af[4], bfr[4];
    #pragma unroll
    for (int mi = 0; mi < 4; mi++)
      af[mi] = *(const bf16x8*)&As[(wr * 64 + mi * 16 + fr) * 32 + sl8];
    #pragma unroll
    for (int ni = 0; ni < 4; ni++)
      bfr[ni] = *(const bf16x8*)&Bs[(wc * 64 + ni * 16 + fr) * 32 + sl8];
    #pragma unroll
    for (int mi = 0; mi < 4; mi++)
      #pragma unroll
      for (int ni = 0; ni < 4; ni++)
        acc[mi][ni] = __builtin_amdgcn_mfma_f32_16x16x32_bf16(af[mi], bfr[ni], acc[mi][ni], 0, 0, 0);
  }
  #pragma unroll
  for (int mi = 0; mi < 4; mi++)
    #pragma unroll
    for (int ni = 0; ni < 4; ni++) {
      const int n = n0 + wc * 64 + ni * 16 + fr;
      #pragma unroll
      for (int i = 0; i < 4; i++) {
        const int m = row0 + wr * 64 + mi * 16 + g * 4 + i;
        dout[(size_t)m * 2048 + n] = f2bf(acc[mi][ni][i] * gatew[m]);
      }
    }
}

// ---------------- fused causal conv+silu+split AND dt softplus ----------------
__global__ __launch_bounds__(256) void conv_silu_dt(
    const float* __restrict__ proj, const float* __restrict__ cw, const float* __restrict__ cb,
    const float* __restrict__ dt_bias,
    float* __restrict__ x, float* __restrict__ Bc, float* __restrict__ Cc,
    float* __restrict__ dt)
{
  const int c = blockIdx.x * 256 + threadIdx.x;
  const int s = blockIdx.y;
  if (c < CONVDIM) {
    const float4 w = *(const float4*)&cw[c * 4];
    float acc = cb[c];
    const float* pc = proj + (size_t)DINNER + c;
    if (s >= 3) acc += pc[(size_t)(s-3) * NPROJP] * w.x;
    if (s >= 2) acc += pc[(size_t)(s-2) * NPROJP] * w.y;
    if (s >= 1) acc += pc[(size_t)(s-1) * NPROJP] * w.z;
    acc += pc[(size_t)s * NPROJP] * w.w;
    const float v = siluf(acc);
    if (c < DINNER)                 x[(size_t)s * DINNER + c] = v;
    else if (c < DINNER + NSTATE)   Bc[(size_t)s * NSTATE + (c - DINNER)] = v;
    else                            Cc[(size_t)s * NSTATE + (c - DINNER - NSTATE)] = v;
  } else if (c < CONVDIM + 64) {
    const int h = c - CONVDIM;
    const float v = proj[(size_t)s * NPROJP + (DINNER + CONVDIM) + h] + dt_bias[h];
    dt[(size_t)s * 64 + h] = fmaxf(v, 0.f) + log1pf(__expf(-fabsf(v)));
  }
}

// ---------------- sequential-order cumsum of dA ----------------
__global__ __launch_bounds__(64) void ssd_cum_seq(
    const float* __restrict__ dt, const float* __restrict__ A_log,
    float* __restrict__ cum, float* __restrict__ cdec)
{
  const int c = blockIdx.x, h = threadIdx.x;
  const float A = -__expf(A_log[h]);
  float run = 0.f;
  float* co = cum + ((size_t)(c * 64 + h)) * 256;
  const float* dp = dt + (size_t)c * 256 * 64 + h;
  #pragma unroll 4
  for (int l = 0; l < 256; l++) {
    run += dp[(size_t)l * 64] * A;
    co[l] = run;
  }
  cdec[c * 64 + h] = __expf(run);
}

// ---------------- CBt ----------------
__global__ __launch_bounds__(256) void ssd_cb(
    const float* __restrict__ Cc, const float* __restrict__ Bc, float* __restrict__ CBt)
{
  const int c = blockIdx.y;
  const int lt = blockIdx.x >> 2, st = blockIdx.x & 3;
  if (st > lt) return;
  __shared__ float Cn[128][64];
  __shared__ float Bn[128][64];
  const int tid = threadIdx.x;
  #pragma unroll
  for (int rep = 0; rep < 8; rep++) {
    const int lin = rep * 1024 + tid * 4;
    const int r = lin >> 7, cc = lin & 127;
    float4 cv = *(const float4*)&Cc[((size_t)(c*256 + lt*64 + r)) * 128 + cc];
    float4 bv = *(const float4*)&Bc[((size_t)(c*256 + st*64 + r)) * 128 + cc];
    Cn[cc+0][r] = cv.x; Cn[cc+1][r] = cv.y; Cn[cc+2][r] = cv.z; Cn[cc+3][r] = cv.w;
    Bn[cc+0][r] = bv.x; Bn[cc+1][r] = bv.y; Bn[cc+2][r] = bv.z; Bn[cc+3][r] = bv.w;
  }
  __syncthreads();
  const int lb = (tid >> 4) * 4, sb = (tid & 15) * 4;
  float acc[4][4] = {};
  for (int n = 0; n < 128; n++) {
    float cv[4], bv[4];
    #pragma unroll
    for (int i = 0; i < 4; i++) { cv[i] = Cn[n][lb+i]; bv[i] = Bn[n][sb+i]; }
    #pragma unroll
    for (int i = 0; i < 4; i++)
      #pragma unroll
      for (int j = 0; j < 4; j++) acc[i][j] += cv[i] * bv[j];
  }
  #pragma unroll
  for (int is = 0; is < 4; is++) {
    const int sg = st*64 + sb + is;
    float4 o; o.x = acc[0][is]; o.y = acc[1][is]; o.z = acc[2][is]; o.w = acc[3][is];
    *(float4*)&CBt[((size_t)(c*256 + sg)) * 256 + lt*64 + lb] = o;
  }
}

// ---------------- intra-chunk Y via MFMA (hi/lo 3-term) ----------------
__global__ __launch_bounds__(256, 2) void ssd_intra_mfma(
    const float* __restrict__ x, const float* __restrict__ dt, const float* __restrict__ cum,
    const float* __restrict__ CBt, float* __restrict__ Yw)
{
  const int c = blockIdx.x, h = blockIdx.y;
  const int tid = threadIdx.x, lane = tid & 63, w = tid >> 6;
  const int fr = lane & 15, g = lane >> 4;
  __shared__ float cumL[256];
  __shared__ u16 Ph[256 * 32], Pl[256 * 32];
  __shared__ u16 Xh[64 * 32],  Xl[64 * 32];
  cumL[tid] = cum[((size_t)(c*64 + h)) * 256 + tid];
  const f32x4 zero = {0.f, 0.f, 0.f, 0.f};
  f32x4 acc[4][4];
  #pragma unroll
  for (int i = 0; i < 4; i++)
    #pragma unroll
    for (int j = 0; j < 4; j++) acc[i][j] = zero;
  const size_t cb0 = (size_t)c * 65536;
  for (int ts = 0; ts < 8; ts++) {
    __syncthreads();
    {   // stage Xd tile (32 s x 64 p) transposed -> Xh/Xl [p][s]
      const int sl = tid >> 3, p0 = (tid & 7) * 8;
      const int sg = c*256 + ts*32 + sl;
      const float dtv = dt[(size_t)sg * 64 + h];
      const float* xr = x + (size_t)sg * DINNER + h*64 + p0;
      const float4 v0 = *(const float4*)&xr[0];
      const float4 v1 = *(const float4*)&xr[4];
      #pragma unroll
      for (int q = 0; q < 8; q++) {
        const float v = ((q < 4) ? ((const float*)&v0)[q] : ((const float*)&v1)[q-4]) * dtv;
        const u16 H = f2bf(v);
        Xh[(p0 + q) * 32 + sl] = H;
        Xl[(p0 + q) * 32 + sl] = f2bf(v - bf2f(H));
      }
    }
    {   // build P tile (256 l x 32 s) hi/lo
      const int l = tid;
      const float myc = cumL[l];
      #pragma unroll 4
      for (int j = 0; j < 32; j++) {
        const int s = ts*32 + j;
        const float cb = CBt[cb0 + (size_t)s * 256 + l];
        float p = 0.f;
        if (s <= l) p = cb * __expf(myc - cumL[s]);
        const u16 H = f2bf(p);
        Ph[l * 32 + j] = H;
        Pl[l * 32 + j] = f2bf(p - bf2f(H));
      }
    }
    __syncthreads();
    if (ts * 32 < (w + 1) * 64) {
      bf16x8 ah[4], al[4], bh[4], bl[4];
      #pragma unroll
      for (int mi = 0; mi < 4; mi++) {
        const int a = (w*64 + mi*16 + fr) * 32 + g*8;
        ah[mi] = *(const bf16x8*)&Ph[a];
        al[mi] = *(const bf16x8*)&Pl[a];
      }
      #pragma unroll
      for (int ni = 0; ni < 4; ni++) {
        const int b = (ni*16 + fr) * 32 + g*8;
        bh[ni] = *(const bf16x8*)&Xh[b];
        bl[ni] = *(const bf16x8*)&Xl[b];
      }
      #pragma unroll
      for (int mi = 0; mi < 4; mi++)
        #pragma unroll
        for (int ni = 0; ni < 4; ni++) {
          acc[mi][ni] = __builtin_amdgcn_mfma_f32_16x16x32_bf16(al[mi], bh[ni], acc[mi][ni], 0, 0, 0);
          acc[mi][ni] = __builtin_amdgcn_mfma_f32_16x16x32_bf16(ah[mi], bl[ni], acc[mi][ni], 0, 0, 0);
          acc[mi][ni] = __builtin_amdgcn_mfma_f32_16x16x32_bf16(ah[mi], bh[ni], acc[mi][ni], 0, 0, 0);
        }
    }
  }
  #pragma unroll
  for (int mi = 0; mi < 4; mi++)
    #pragma unroll
    for (int ni = 0; ni < 4; ni++)
      #pragma unroll
      for (int i = 0; i < 4; i++) {
        const int l = w*64 + mi*16 + g*4 + i;
        const int p = ni*16 + fr;
        Yw[(size_t)(c*256 + l) * DINNER + h*64 + p] = acc[mi][ni][i];
      }
}

// ---------------- chunk states via MFMA (hi/lo 3-term) ----------------
__global__ __launch_bounds__(256, 2) void ssd_states_mfma(
    const float* __restrict__ x, const float* __restrict__ Bc, const float* __restrict__ dt,
    const float* __restrict__ cum, float* __restrict__ states)
{
  const int c = blockIdx.x, h = blockIdx.y;
  const int tid = threadIdx.x, lane = tid & 63, w = tid >> 6;
  const int fr = lane & 15, g = lane >> 4;
  __shared__ float cd[256];
  __shared__ u16 Xth[64 * 32],  Xtl[64 * 32];
  __shared__ u16 Bth[128 * 32], Btl[128 * 32];
  {
    const float* cumh = cum + ((size_t)(c*64 + h)) * 256;
    cd[tid] = __expf(cumh[255] - cumh[tid]) * dt[(size_t)(c*256 + tid) * 64 + h];
  }
  const f32x4 zero = {0.f, 0.f, 0.f, 0.f};
  f32x4 acc[4][2];
  #pragma unroll
  for (int i = 0; i < 4; i++) { acc[i][0] = zero; acc[i][1] = zero; }
  for (int lt = 0; lt < 8; lt++) {
    __syncthreads();
    {
      const int ll = tid >> 3, p0 = (tid & 7) * 8;
      const int lg = c*256 + lt*32 + ll;
      const float cdv = cd[lt*32 + ll];
      const float* xr = x + (size_t)lg * DINNER + h*64 + p0;
      const float4 v0 = *(const float4*)&xr[0];
      const float4 v1 = *(const float4*)&xr[4];
      #pragma unroll
      for (int q = 0; q < 8; q++) {
        const float v = ((q < 4) ? ((const float*)&v0)[q] : ((const float*)&v1)[q-4]) * cdv;
        const u16 H = f2bf(v);
        Xth[(p0 + q) * 32 + ll] = H;
        Xtl[(p0 + q) * 32 + ll] = f2bf(v - bf2f(H));
      }
    }
    {
      const int ll = tid >> 3, n0 = (tid & 7) * 16;
      const float* br = Bc + (size_t)(c*256 + lt*32 + ll) * 128 + n0;
      #pragma unroll
      for (int q4 = 0; q4 < 4; q4++) {
        const float4 bv = *(const float4*)&br[q4*4];
        #pragma unroll
        for (int q = 0; q < 4; q++) {
          const float v = ((const float*)&bv)[q];
          const u16 H = f2bf(v);
          Bth[(n0 + q4*4 + q) * 32 + ll] = H;
          Btl[(n0 + q4*4 + q) * 32 + ll] = f2bf(v - bf2f(H));
        }
      }
    }
    __syncthreads();
    bf16x8 ah[4], al[4], bh[2], bl[2];
    #pragma unroll
    for (int mi = 0; mi < 4; mi++) {
      const int a = (mi*16 + fr) * 32 + g*8;
      ah[mi] = *(const bf16x8*)&Xth[a];
      al[mi] = *(const bf16x8*)&Xtl[a];
    }
    #pragma unroll
    for (int ni = 0; ni < 2; ni++) {
      const int b = (w*32 + ni*16 + fr) * 32 + g*8;
      bh[ni] = *(const bf16x8*)&Bth[b];
      bl[ni] = *(const bf16x8*)&Btl[b];
    }
    #pragma unroll
    for (int mi = 0; mi < 4; mi++)
      #pragma unroll
      for (int ni = 0; ni < 2; ni++) {
        acc[mi][ni] = __builtin_amdgcn_mfma_f32_16x16x32_bf16(al[mi], bh[ni], acc[mi][ni], 0, 0, 0);
        acc[mi][ni] = __builtin_amdgcn_mfma_f32_16x16x32_bf16(ah[mi], bl[ni], acc[mi][ni], 0, 0, 0);
        acc[mi][ni] = __builtin_amdgcn_mfma_f32_16x16x32_bf16(ah[mi], bh[ni], acc[mi][ni], 0, 0, 0);
      }
  }
  #pragma unroll
  for (int mi = 0; mi < 4; mi++)
    #pragma unroll
    for (int ni = 0; ni < 2; ni++)
      #pragma unroll
      for (int i = 0; i < 4; i++) {
        const int p = mi*16 + g*4 + i;
        const int n = w*32 + ni*16 + fr;
        states[(((size_t)(c*64 + h)) * 64 + p) * 128 + n] = acc[mi][ni][i];
      }
}

// ---------------- sequential scan over the 16 chunks ----------------
__global__ void ssd_scan(
    const float* __restrict__ states, const float* __restrict__ cdec, float* __restrict__ prev)
{
  const int hp = blockIdx.x;
  const int n = threadIdx.x;
  const int h = hp >> 6;
  float carry = 0.f;
  for (int c = 0; c < NCHUNK; c++) {
    const size_t idx = ((size_t)c * 4096 + hp) * 128 + n;
    prev[idx] = carry;
    carry = carry * cdec[c*64 + h] + states[idx];
  }
}

// ---------------- inter-chunk Y via MFMA (3-term) + D*x + silu(z) gating ----------------
__global__ __launch_bounds__(256, 2) void ssd_final_mfma(
    const float* __restrict__ Cc, const float* __restrict__ prev, const float* __restrict__ cum,
    const float* __restrict__ x, const float* __restrict__ proj, const float* __restrict__ Dp,
    float* __restrict__ Yw)
{
  const int c = blockIdx.x, h = blockIdx.y;
  const int tid = threadIdx.x, lane = tid & 63, w = tid >> 6;
  const int fr = lane & 15, g = lane >> 4;
  __shared__ float cumL[256];
  __shared__ u16 Ch[256 * 32], Cl[256 * 32];
  __shared__ u16 Pvh[64 * 32], Pvl[64 * 32];
  cumL[tid] = cum[((size_t)(c*64 + h)) * 256 + tid];
  const f32x4 zero = {0.f, 0.f, 0.f, 0.f};
  f32x4 acc[4][4];
  #pragma unroll
  for (int i = 0; i < 4; i++)
    #pragma unroll
    for (int j = 0; j < 4; j++) acc[i][j] = zero;
  for (int nt = 0; nt < 4; nt++) {
    __syncthreads();
    {
      #pragma unroll
      for (int rep = 0; rep < 32; rep++) {
        const int l = rep*8 + (tid >> 5);
        const int j = tid & 31;
        const float v = Cc[(size_t)(c*256 + l) * 128 + nt*32 + j];
        const u16 H = f2bf(v);
        Ch[l*32 + j] = H;
        Cl[l*32 + j] = f2bf(v - bf2f(H));
      }
    }
    {
      const int p = tid >> 2, q0 = (tid & 3) * 8;
      const float* pr = prev + ((size_t)c * 4096 + h*64 + p) * 128 + nt*32 + q0;
      const float4 v0 = *(const float4*)&pr[0];
      const float4 v1 = *(const float4*)&pr[4];
      #pragma unroll
      for (int q = 0; q < 8; q++) {
        const float v = (q < 4) ? ((const float*)&v0)[q] : ((const float*)&v1)[q-4];
        const u16 H = f2bf(v);
        Pvh[p*32 + q0 + q] = H;
        Pvl[p*32 + q0 + q] = f2bf(v - bf2f(H));
      }
    }
    __syncthreads();
    bf16x8 ah[4], al[4], bh[4], bl[4];
    #pragma unroll
    for (int mi = 0; mi < 4; mi++) {
      const int a = (w*64 + mi*16 + fr) * 32 + g*8;
      ah[mi] = *(const bf16x8*)&Ch[a];
      al[mi] = *(const bf16x8*)&Cl[a];
    }
    #pragma unroll
    for (int ni = 0; ni < 4; ni++) {
      const int b = (ni*16 + fr) * 32 + g*8;
      bh[ni] = *(const bf16x8*)&Pvh[b];
      bl[ni] = *(const bf16x8*)&Pvl[b];
    }
    #pragma unroll
    for (int mi = 0; mi < 4; mi++)
      #pragma unroll
      for (int ni = 0; ni < 4; ni++) {
        acc[mi][ni] = __builtin_amdgcn_mfma_f32_16x16x32_bf16(al[mi], bh[ni], acc[mi][ni], 0, 0, 0);
        acc[mi][ni] = __builtin_amdgcn_mfma_f32_16x16x32_bf16(ah[mi], bl[ni], acc[mi][ni], 0, 0, 0);
        acc[mi][ni] = __builtin_amdgcn_mfma_f32_16x16x32_bf16(ah[mi], bh[ni], acc[mi][ni], 0, 0, 0);
      }
  }
  const float Dv = Dp[h];
  #pragma unroll
  for (int mi = 0; mi < 4; mi++) {
    #pragma unroll
    for (int i = 0; i < 4; i++) {
      const int l = w*64 + mi*16 + g*4 + i;
      const float odec = __expf(cumL[l]);
      const size_t rowo = (size_t)(c*256 + l);
      #pragma unroll
      for (int ni = 0; ni < 4; ni++) {
        const int p = ni*16 + fr;
        const size_t iy = rowo * DINNER + h*64 + p;
        const float yv = Yw[iy] + acc[mi][ni][i] * odec + Dv * x[iy];
        const float z = proj[rowo * NPROJP + h*64 + p];
        Yw[iy] = yv * siluf(z);
      }
    }
  }
}

// ---------------- fused: rmsnorm(hidden2)->ht bf16 AND router top-2 ----------------
__global__ __launch_bounds__(256) void router_norm(
    const float* __restrict__ h2, const float* __restrict__ ln2w,
    const float* __restrict__ rw, u16* __restrict__ ht,
    int* __restrict__ eidx, float* __restrict__ ew)
{
  const int t = blockIdx.x;
  const float* xr = h2 + (size_t)t * DMODEL;
  float ss = 0.f;
  for (int i = threadIdx.x * 4; i < DMODEL; i += 1024) {
    float4 v = *(const float4*)&xr[i];
    ss += v.x*v.x + v.y*v.y + v.z*v.z + v.w*v.w;
  }
  #pragma unroll
  for (int off = 32; off > 0; off >>= 1) ss += __shfl_down(ss, off);
  __shared__ float red[4];
  if ((threadIdx.x & 63) == 0) red[threadIdx.x >> 6] = ss;
  __syncthreads();
  const float scale = rsqrtf((red[0]+red[1]+red[2]+red[3]) / (float)DMODEL + 1e-5f);
  float acc[8];
  #pragma unroll
  for (int j = 0; j < 8; j++) acc[j] = 0.f;
  u16* o = ht + (size_t)t * DMODEL;
  for (int i = threadIdx.x; i < DMODEL; i += 256) {
    const float v = xr[i] * scale * ln2w[i];
    o[i] = f2bf(v);
    const float* r = rw + (size_t)i * 8;
    #pragma unroll
    for (int j = 0; j < 8; j++) acc[j] += v * r[j];
  }
  #pragma unroll
  for (int j = 0; j < 8; j++)
    #pragma unroll
    for (int off = 32; off > 0; off >>= 1) acc[j] += __shfl_down(acc[j], off);
  __shared__ float rbuf[4][8];
  if ((threadIdx.x & 63) == 0)
    #pragma unroll
    for (int j = 0; j < 8; j++) rbuf[threadIdx.x >> 6][j] = acc[j];
  __syncthreads();
  if (threadIdx.x == 0) {
    float lg[8];
    #pragma unroll
    for (int j = 0; j < 8; j++) lg[j] = rbuf[0][j]+rbuf[1][j]+rbuf[2][j]+rbuf[3][j];
    int i1 = 0;
    #pragma unroll
    for (int j = 1; j < 8; j++) if (lg[j] > lg[i1]) i1 = j;
    int i2 = -1;
    #pragma unroll
    for (int j = 0; j < 8; j++) if (j != i1 && (i2 < 0 || lg[j] > lg[i2])) i2 = j;
    const float e2 = __expf(lg[i2] - lg[i1]);
    const float inv = 1.f / (1.f + e2);
    eidx[t*2]   = i1;  ew[t*2]   = inv;
    eidx[t*2+1] = i2;  ew[t*2+1] = e2 * inv;
  }
}

// ---------------- single-block MoE routing: zero + count + offsets + place ----------------
__global__ __launch_bounds__(1024) void moe_route(
    const int* __restrict__ eidx, const float* __restrict__ ew,
    int* __restrict__ tokmap, float* __restrict__ gatew,
    int* __restrict__ posmap, int* __restrict__ meta)
{
  const int tid = threadIdx.x;
  __shared__ int cnt[8], base[8];
  if (tid < 8) cnt[tid] = 0;
  for (int i = tid; i < MAXROWS; i += 1024) tokmap[i] = 0;
  __syncthreads();
  for (int i = tid; i < SEQ * 2; i += 1024)
    atomicAdd(&cnt[eidx[i]], 1);
  __syncthreads();
  if (tid == 0) {
    int off = 0, T = 0;
    for (int e = 0; e < 8; e++) {
      base[e] = off;
      meta[16 + e] = off;
      const int nt = (cnt[e] + 127) >> 7;
      for (int j = 0; j < nt; j++) {
        meta[32 + T] = e;
        meta[104 + T] = off + j * 128;
        T++;
      }
      off += nt * 128;
      cnt[e] = 0;
    }
    meta[24] = T;
  }
  __syncthreads();
  for (int i = tid; i < SEQ * 2; i += 1024) {
    const int e = eidx[i];
    const int pos = atomicAdd(&cnt[e], 1);
    const int r = base[e] + pos;
    tokmap[r] = i >> 1;
    gatew[r] = ew[i];
    posmap[i] = r;
  }
}

// ---------------- out0 = h2 + RESM*(shared + dout[pos0] + dout[pos1]) ----------------
__global__ __launch_bounds__(256) void final_moe(
    const float* __restrict__ h2, const float* __restrict__ shout,
    const u16* __restrict__ dout, const int* __restrict__ posmap,
    float* __restrict__ o)
{
  const int t = blockIdx.x;
  const int p0 = posmap[t*2], p1 = posmap[t*2+1];
  const u16* d0 = dout + (size_t)p0 * 2048 + threadIdx.x * 8;
  const u16* d1 = dout + (size_t)p1 * 2048 + threadIdx.x * 8;
  const size_t base = (size_t)t * 2048 + threadIdx.x * 8;
  #pragma unroll
  for (int q = 0; q < 8; q++) {
    const float ff = shout[base + q] + bf2f(d0[q]) + bf2f(d1[q]);
    o[base + q] = h2[base + q] + RESM * ff;
  }
}

// ---------------- workspace layout (bytes) ----------------
#define OFF_WAH   ((size_t)0)
#define OFF_WAL   ((size_t)35127296)
#define OFF_PROJ  ((size_t)70254592)
#define OFF_X     ((size_t)210763776)
#define OFF_Y     ((size_t)277872640)
#define OFF_HP    ((size_t)344981504)
#define OFF_BC    ((size_t)378535936)
#define OFF_CC    ((size_t)380633088)
#define OFF_DT    ((size_t)382730240)
#define OFF_CUM   ((size_t)383778816)
#define OFF_CDEC  ((size_t)384827392)
#define OFF_CB    ((size_t)384831488)

extern "C" void kernel_launch(void* const* d_in, const int* in_sizes, int n_in,
                              void* d_out, int out_size, void* d_ws, size_t ws_size,
                              hipStream_t stream)
{
  const float* hs       = (const float*)d_in[1];
  const float* ln1_w    = (const float*)d_in[2];
  const float* w_inproj = (const float*)d_in[3];
  const float* conv_w   = (const float*)d_in[4];
  const float* conv_b   = (const float*)d_in[5];
  const float* A_log    = (const float*)d_in[6];
  const float* dt_bias  = (const float*)d_in[7];
  const float* D_param  = (const float*)d_in[8];
  const float* mnorm_w  = (const float*)d_in[9];
  const float* w_outp   = (const float*)d_in[10];
  const float* ln2_w    = (const float*)d_in[11];
  const float* router_w = (const float*)d_in[12];
  const float* w_gu     = (const float*)d_in[13];
  const float* w_down   = (const float*)d_in[14];
  const float* w_shin   = (const float*)d_in[15];
  const float* w_shout  = (const float*)d_in[16];

  char* ws = (char*)d_ws;
  u16*   wAh    = (u16*)(ws + OFF_WAH);
  u16*   wAl    = (u16*)(ws + OFF_WAL);
  float* projf  = (float*)(ws + OFF_PROJ);
  float* xbuf   = (float*)(ws + OFF_X);
  float* ybuf   = (float*)(ws + OFF_Y);
  float* Bcb    = (float*)(ws + OFF_BC);
  float* Ccb    = (float*)(ws + OFF_CC);
  float* dtb    = (float*)(ws + OFF_DT);
  float* cumb   = (float*)(ws + OFF_CUM);
  float* cdecb  = (float*)(ws + OFF_CDEC);
  float* cbt    = (float*)(ws + OFF_CB);

  // lifetime-overlapped aliases
  u16*   hhi    = (u16*)(ws + OFF_HP);
  u16*   hlo    = (u16*)(ws + OFF_HP + 16777216);
  float* prevb  = (float*)(ws + OFF_HP);
  u16*   wDN    = (u16*)(ws + OFF_HP);                   // 32MiB after prev dead
  float* stbuf  = (float*)(ws + OFF_WAH);
  u16*   ynhi   = (u16*)(ws + OFF_WAH);
  u16*   ynlo   = (u16*)(ws + OFF_WAL);
  u16*   wBh    = (u16*)(ws + OFF_PROJ);
  u16*   wBl    = (u16*)(ws + OFF_PROJ + 16777216);
  u16*   wE     = (u16*)(ws + OFF_WAH);                  // shared-in Wt interleaved (33.5M)
  u16*   wD     = (u16*)(ws + OFF_WAH + 33554432);       // shared-out Wt (16.8M)
  u16*   wGU    = (u16*)(ws + OFF_WAH);                  // expert gate_up Wt interleaved (64M)
  u16*   abufp  = (u16*)(ws + OFF_PROJ + 83886080);      // packed a bf16 (18.9M)
  u16*   ht     = (u16*)(ws + OFF_X);
  u16*   ash    = (u16*)(ws + OFF_X + 16777216);         // shared a bf16 (33.5M)
  u16*   dout   = (u16*)(ws + OFF_X + 16777216);         // packed dout bf16, after ash dead
  float* shout  = (float*)(ws + OFF_Y);

  int*   eidx   = (int*)(ws + OFF_BC);
  float* ew     = (float*)(ws + OFF_BC + 65536);
  int*   posmap = (int*)(ws + OFF_BC + 131072);
  int*   tokmap = (int*)(ws + OFF_BC + 196608);
  float* gatew  = (float*)(ws + OFF_BC + 262144);
  int*   meta   = (int*)(ws + OFF_BC + 327680);

  float* out0    = (float*)d_out;
  float* hidden2 = out0 + (size_t)SEQ * DMODEL;

  // ---- Mamba block ----
  rmsnorm_split<<<SEQ, 256, 0, stream>>>(hs, ln1_w, hhi, hlo, DMODEL);
  wconv_t_split<<<dim3(NPROJ/32, DMODEL/32), 256, 0, stream>>>(w_inproj, wAh, wAl, DMODEL, NPROJ);
  gemm_dd<3><<<67*32, 256, 0, stream>>>(hhi, hlo, wAh, wAl, projf, nullptr,
                                        NPROJ, DMODEL, NPROJP, 0.f, 67, 32, 4);
  conv_silu_dt<<<dim3(18, SEQ), 256, 0, stream>>>(projf, conv_w, conv_b, dt_bias,
                                                  xbuf, Bcb, Ccb, dtb);
  ssd_cum_seq<<<NCHUNK, 64, 0, stream>>>(dtb, A_log, cumb, cdecb);
  ssd_cb<<<dim3(16, NCHUNK), 256, 0, stream>>>(Ccb, Bcb, cbt);
  ssd_intra_mfma<<<dim3(NCHUNK, NHEADS), 256, 0, stream>>>(xbuf, dtb, cumb, cbt, ybuf);
  ssd_states_mfma<<<dim3(NCHUNK, NHEADS), 256, 0, stream>>>(xbuf, Bcb, dtb, cumb, stbuf);
  ssd_scan<<<NHEADS*HEADP, 128, 0, stream>>>(stbuf, cdecb, prevb);
  ssd_final_mfma<<<dim3(NCHUNK, NHEADS), 256, 0, stream>>>(Ccb, prevb, cumb, xbuf, projf, D_param, ybuf);
  rmsnorm_split<<<SEQ, 256, 0, stream>>>(ybuf, mnorm_w, ynhi, ynlo, DINNER);
  wconv_t_split<<<dim3(DMODEL/32, DINNER/32), 256, 0, stream>>>(w_outp, wBh, wBl, DINNER, DMODEL);
  gemm_dd<1><<<16*32, 256, 0, stream>>>(ynhi, ynlo, wBh, wBl, hidden2, hs,
                                        DMODEL, DINNER, DMODEL, RESM, 16, 32, 4);

  // ---- Router + ht norm (fused) + single-kernel token packing ----
  router_norm<<<SEQ, 256, 0, stream>>>(hidden2, ln2_w, router_w, ht, eidx, ew);
  moe_route<<<1, 1024, 0, stream>>>(eidx, ew, tokmap, gatew, posmap, meta);

  // ---- Shared expert (dense, GLU fused into gate_up GEMM) ----
  wconv_t_glu<<<dim3(8192/32, DMODEL/32), 256, 0, stream>>>(w_shin, wE, DMODEL, 8192, 4096);
  gemm_bt_glu<<<64*32, 256, 0, stream>>>(ht, wE, ash, DMODEL, 4096, 64, 32, 4);
  wconv_t<<<dim3(DMODEL/32, 4096/32), 256, 0, stream>>>(w_shout, wD, 4096, DMODEL);
  gemm_bt<3><<<16*32, 256, 0, stream>>>(ash, wD, shout, DMODEL, 4096, DMODEL, 16, 32, 4);

  // ---- Sparse top-2 experts (packed, GLU fused) ----
  wconv_t_glu<<<dim3(2048/32, DMODEL/32, 8), 256, 0, stream>>>(w_gu, wGU, DMODEL, 2048, 1024);
  wconv_t<<<dim3(DMODEL/32, 1024/32, 8), 256, 0, stream>>>(w_down, wDN, 1024, DMODEL);
  gemm_moe_gu<<<dim3(16, MAXTILE), 256, 0, stream>>>(ht, wGU, abufp, tokmap, meta);
  gemm_moe_down<<<dim3(16, MAXTILE), 256, 0, stream>>>(abufp, wDN, dout, gatew, meta);

  final_moe<<<SEQ, 256, 0, stream>>>(hidden2, shout, dout, posmap, out0);
}